// Round 1
// baseline (787.131 us; speedup 1.0000x reference)
//
#include <hip/hip_runtime.h>

typedef unsigned int u32;

#define Tn 4
#define Bn 32
#define Cn 384
#define Nn 196
#define Hn 12
#define CNn (Cn*Nn)         // 75264
#define BCNn (Bn*CNn)       // 2408448
#define BHNn (Bn*Hn*Nn)     // 75264
#define PBITS (Tn*BHNn)     // 301056
#define TBCNn (Tn*BCNn)     // 9633792

// ---------------------------------------------------------------------------
// K1: per-t channel GEMM + BN:  Y[t,b,o,n] = BN( sum_c W[o,c] * X[t,b,c,n] )
// GEMM view: [384 o] x [6272 cols=(b,n)] with K=384. Block tile 128x128,
// thread tile 8x8, LDS-staged, float4 loads/stores throughout.
// ---------------------------------------------------------------------------
__global__ __launch_bounds__(256) void gemm_bn(
    const float* __restrict__ X, const float* __restrict__ W,
    const float* __restrict__ gamma, const float* __restrict__ beta,
    const float* __restrict__ mean, const float* __restrict__ var,
    float* __restrict__ Y)
{
  __shared__ float Xs[16][132];
  __shared__ float Ws[16][132];
  const int tid = threadIdx.x;
  const int tx = tid & 15, ty = tid >> 4;
  const int col0 = blockIdx.x * 128;
  const int o0 = blockIdx.y * 128;
  const int t = blockIdx.z;

  // X staging map: 2 float4 per thread, covering 16c x 128col
  const int xi1 = tid + 256;
  const int xc0 = tid >> 5, xcol0 = (tid & 31) * 4;
  const int xc1 = xi1 >> 5, xcol1 = (xi1 & 31) * 4;
  const int cg0 = col0 + xcol0; const int bg0 = cg0 / Nn; const int ng0 = cg0 - bg0 * Nn;
  const int cg1 = col0 + xcol1; const int bg1 = cg1 / Nn; const int ng1 = cg1 - bg1 * Nn;
  const float* Xp0 = X + (size_t)t * BCNn + (size_t)bg0 * CNn + ng0;
  const float* Xp1 = X + (size_t)t * BCNn + (size_t)bg1 * CNn + ng1;
  // W staging map: 2 float4 per thread, covering 128o x 16c (transposed to LDS)
  const int wo0 = tid >> 2;
  const int wc0 = (tid & 3) * 4;
  const float* Wp0 = W + (size_t)(o0 + wo0) * Cn + wc0;
  const float* Wp1 = W + (size_t)(o0 + wo0 + 64) * Cn + wc0;

  float acc[8][8] = {};

  for (int kk = 0; kk < 24; ++kk) {
    float4 xa = *(const float4*)(Xp0 + (size_t)(kk * 16 + xc0) * Nn);
    float4 xb = *(const float4*)(Xp1 + (size_t)(kk * 16 + xc1) * Nn);
    float4 wa = *(const float4*)(Wp0 + kk * 16);
    float4 wb = *(const float4*)(Wp1 + kk * 16);
    *(float4*)(&Xs[xc0][xcol0]) = xa;
    *(float4*)(&Xs[xc1][xcol1]) = xb;
    Ws[wc0 + 0][wo0] = wa.x; Ws[wc0 + 1][wo0] = wa.y;
    Ws[wc0 + 2][wo0] = wa.z; Ws[wc0 + 3][wo0] = wa.w;
    Ws[wc0 + 0][wo0 + 64] = wb.x; Ws[wc0 + 1][wo0 + 64] = wb.y;
    Ws[wc0 + 2][wo0 + 64] = wb.z; Ws[wc0 + 3][wo0 + 64] = wb.w;
    __syncthreads();
#pragma unroll
    for (int cs = 0; cs < 16; ++cs) {
      float xr[8], wr[8];
      *(float4*)&xr[0] = *(const float4*)(&Xs[cs][tx * 8]);
      *(float4*)&xr[4] = *(const float4*)(&Xs[cs][tx * 8 + 4]);
      *(float4*)&wr[0] = *(const float4*)(&Ws[cs][ty * 8]);
      *(float4*)&wr[4] = *(const float4*)(&Ws[cs][ty * 8 + 4]);
#pragma unroll
      for (int i = 0; i < 8; i++)
#pragma unroll
        for (int j = 0; j < 8; j++)
          acc[i][j] += wr[i] * xr[j];
    }
    __syncthreads();
  }

  // epilogue: BN (eval mode) + store. Each 8-col frag may straddle a b
  // boundary only at a float4 granularity (col % 4 == 0 always).
  const int colA = col0 + tx * 8; const int bA = colA / Nn, nA = colA - bA * Nn;
  const int colB = colA + 4;      const int bB = colB / Nn, nB = colB - bB * Nn;
  float* YA = Y + (size_t)t * BCNn + (size_t)bA * CNn + nA;
  float* YB = Y + (size_t)t * BCNn + (size_t)bB * CNn + nB;
#pragma unroll
  for (int i = 0; i < 8; i++) {
    const int o = o0 + ty * 8 + i;
    const float iv = gamma[o] / sqrtf(var[o] + 1e-5f);
    const float sh = beta[o] - mean[o] * iv;
    float4 ra, rb;
    ra.x = acc[i][0] * iv + sh; ra.y = acc[i][1] * iv + sh;
    ra.z = acc[i][2] * iv + sh; ra.w = acc[i][3] * iv + sh;
    rb.x = acc[i][4] * iv + sh; rb.y = acc[i][5] * iv + sh;
    rb.z = acc[i][6] * iv + sh; rb.w = acc[i][7] * iv + sh;
    *(float4*)(YA + (size_t)o * Nn) = ra;
    *(float4*)(YB + (size_t)o * Nn) = rb;
  }
}

// ---------------------------------------------------------------------------
// K2: LIF over T (v_th = 1.0) + pack 32 channels (one head) into a uint32.
// One thread per (b,h,n). bits[t*BHN + (b*H+h)*N + n], bit d = spike.
// ---------------------------------------------------------------------------
__global__ __launch_bounds__(256) void lif_pack(
    const float* __restrict__ Y, u32* __restrict__ bits)
{
  const int idx = blockIdx.x * 256 + threadIdx.x;  // < 75264 exactly
  const int n = idx % Nn;
  const int hb = idx / Nn;
  const int h = hb % Hn;
  const int b = hb / Hn;
  float v[32];
#pragma unroll
  for (int d = 0; d < 32; d++) v[d] = 0.f;
#pragma unroll
  for (int t = 0; t < Tn; t++) {
    const float* p = Y + (size_t)(t * Bn + b) * CNn + (size_t)(h * 32) * Nn + n;
    u32 m = 0;
#pragma unroll
    for (int d = 0; d < 32; d++) {
      const float x = p[(size_t)d * Nn];
      const float vv = v[d] + (x - v[d]) * 0.5f;
      const bool sp = vv >= 1.0f;
      m |= (u32)(sp ? 1u : 0u) << d;
      v[d] = sp ? 0.f : vv;
    }
    bits[(size_t)t * BHNn + idx] = m;
  }
}

// ---------------------------------------------------------------------------
// K3: attention per (t,b,h). attn[n,m]=popc(q[n]&k[m]) (exact), masked by
// policy (diag unmasked), y[n,d]=0.25*sum_m attn*mask*v[m,d].
// ---------------------------------------------------------------------------
__global__ __launch_bounds__(256) void attn_kernel(
    const u32* __restrict__ qb, const u32* __restrict__ kb,
    const u32* __restrict__ vb, const float* __restrict__ policy,
    float* __restrict__ Y)
{
  __shared__ u32 qs[Nn], ks[Nn], vs[Nn];
  __shared__ float ps[Nn];
  __shared__ float vf[Nn * 32];
  const int gid = blockIdx.x;          // (t*B+b)*H + h
  const int tb = gid / Hn;             // t*B+b
  const int h = gid - tb * Hn;
  const int tid = threadIdx.x;
  for (int i = tid; i < Nn; i += 256) {
    qs[i] = qb[(size_t)gid * Nn + i];
    ks[i] = kb[(size_t)gid * Nn + i];
    vs[i] = vb[(size_t)gid * Nn + i];
    ps[i] = policy[(size_t)tb * Nn + i];
  }
  __syncthreads();
  for (int i = tid; i < Nn * 32; i += 256)
    vf[i] = (float)((vs[i >> 5] >> (i & 31)) & 1u);
  __syncthreads();
  const int n = tid;
  if (n < Nn) {
    const u32 qn = qs[n];
    float acc[32];
#pragma unroll
    for (int d = 0; d < 32; d++) acc[d] = 0.f;
    for (int m = 0; m < Nn; m++) {
      const u32 a = __popc(qn & ks[m]);
      if (a) {  // skipping adds exact zeros: fp32 sum unchanged
        const float pm = ps[m];
        const float mask = (m == n) ? (pm + (1.0f - pm)) : pm;
        const float w = (float)a * mask;
        const float4* vr = (const float4*)(vf + m * 32);
#pragma unroll
        for (int q = 0; q < 8; q++) {
          const float4 vv = vr[q];
          acc[q * 4 + 0] += w * vv.x; acc[q * 4 + 1] += w * vv.y;
          acc[q * 4 + 2] += w * vv.z; acc[q * 4 + 3] += w * vv.w;
        }
      }
    }
    const int t = tb / Bn, b = tb - (tb / Bn) * Bn;
    float* outp = Y + (size_t)t * BCNn + (size_t)b * CNn + (size_t)(h * 32) * Nn + n;
#pragma unroll
    for (int d = 0; d < 32; d++) outp[(size_t)d * Nn] = acc[d] * 0.25f;
  }
}

// ---------------------------------------------------------------------------
// K4: in-place LIF over T (v_th param). Per-thread same addresses -> safe.
// ---------------------------------------------------------------------------
__global__ __launch_bounds__(256) void lif_inplace(float* __restrict__ Y, float thr)
{
  const size_t pos = (size_t)blockIdx.x * 256 + threadIdx.x;  // < BCN exactly
  float v = 0.f;
#pragma unroll
  for (int t = 0; t < Tn; t++) {
    const float x = Y[(size_t)t * BCNn + pos];
    v = v + (x - v) * 0.5f;
    const bool sp = v >= thr;
    Y[(size_t)t * BCNn + pos] = sp ? 1.0f : 0.0f;
    v = sp ? 0.f : v;
  }
}

// ---------------------------------------------------------------------------
// K5: proj GEMM + bias + BN + final LIF (v_th=1.0) fused; t-loop inside so
// LIF state lives in registers. Writes binary fp32 output.
// ---------------------------------------------------------------------------
__global__ __launch_bounds__(256) void gemm_bn_lif(
    const float* __restrict__ X, const float* __restrict__ W,
    const float* __restrict__ gamma, const float* __restrict__ beta,
    const float* __restrict__ mean, const float* __restrict__ var,
    const float* __restrict__ bias, float* __restrict__ Out)
{
  __shared__ float Xs[16][132];
  __shared__ float Ws[16][132];
  const int tid = threadIdx.x;
  const int tx = tid & 15, ty = tid >> 4;
  const int col0 = blockIdx.x * 128;
  const int o0 = blockIdx.y * 128;

  const int xi1 = tid + 256;
  const int xc0 = tid >> 5, xcol0 = (tid & 31) * 4;
  const int xc1 = xi1 >> 5, xcol1 = (xi1 & 31) * 4;
  const int cg0 = col0 + xcol0; const int bg0 = cg0 / Nn; const int ng0 = cg0 - bg0 * Nn;
  const int cg1 = col0 + xcol1; const int bg1 = cg1 / Nn; const int ng1 = cg1 - bg1 * Nn;
  const float* Xb0 = X + (size_t)bg0 * CNn + ng0;
  const float* Xb1 = X + (size_t)bg1 * CNn + ng1;
  const int wo0 = tid >> 2;
  const int wc0 = (tid & 3) * 4;
  const float* Wp0 = W + (size_t)(o0 + wo0) * Cn + wc0;
  const float* Wp1 = W + (size_t)(o0 + wo0 + 64) * Cn + wc0;

  // BN + bias constants for this thread's 8 output rows
  float iv8[8], sh8[8], pb8[8];
#pragma unroll
  for (int i = 0; i < 8; i++) {
    const int o = o0 + ty * 8 + i;
    const float iv = gamma[o] / sqrtf(var[o] + 1e-5f);
    iv8[i] = iv; sh8[i] = beta[o] - mean[o] * iv; pb8[i] = bias[o];
  }

  const int colA = col0 + tx * 8; const int bA = colA / Nn, nA = colA - bA * Nn;
  const int colB = colA + 4;      const int bB = colB / Nn, nB = colB - bB * Nn;
  float* OA = Out + (size_t)bA * CNn + nA;
  float* OB = Out + (size_t)bB * CNn + nB;

  float vst[8][8] = {};

  for (int t = 0; t < Tn; t++) {
    float acc[8][8] = {};
    const float* Xp0 = Xb0 + (size_t)t * BCNn;
    const float* Xp1 = Xb1 + (size_t)t * BCNn;
    for (int kk = 0; kk < 24; ++kk) {
      float4 xa = *(const float4*)(Xp0 + (size_t)(kk * 16 + xc0) * Nn);
      float4 xb = *(const float4*)(Xp1 + (size_t)(kk * 16 + xc1) * Nn);
      float4 wa = *(const float4*)(Wp0 + kk * 16);
      float4 wb = *(const float4*)(Wp1 + kk * 16);
      *(float4*)(&Xs[xc0][xcol0]) = xa;
      *(float4*)(&Xs[xc1][xcol1]) = xb;
      Ws[wc0 + 0][wo0] = wa.x; Ws[wc0 + 1][wo0] = wa.y;
      Ws[wc0 + 2][wo0] = wa.z; Ws[wc0 + 3][wo0] = wa.w;
      Ws[wc0 + 0][wo0 + 64] = wb.x; Ws[wc0 + 1][wo0 + 64] = wb.y;
      Ws[wc0 + 2][wo0 + 64] = wb.z; Ws[wc0 + 3][wo0 + 64] = wb.w;
      __syncthreads();
#pragma unroll
      for (int cs = 0; cs < 16; ++cs) {
        float xr[8], wr[8];
        *(float4*)&xr[0] = *(const float4*)(&Xs[cs][tx * 8]);
        *(float4*)&xr[4] = *(const float4*)(&Xs[cs][tx * 8 + 4]);
        *(float4*)&wr[0] = *(const float4*)(&Ws[cs][ty * 8]);
        *(float4*)&wr[4] = *(const float4*)(&Ws[cs][ty * 8 + 4]);
#pragma unroll
        for (int i = 0; i < 8; i++)
#pragma unroll
          for (int j = 0; j < 8; j++)
            acc[i][j] += wr[i] * xr[j];
      }
      __syncthreads();
    }
    // epilogue: (acc + b) * inv + sh, then LIF step, write spikes
#pragma unroll
    for (int i = 0; i < 8; i++) {
      const int o = o0 + ty * 8 + i;
      float rr[8];
#pragma unroll
      for (int j = 0; j < 8; j++) {
        const float z = (acc[i][j] + pb8[i]) * iv8[i] + sh8[i];
        const float v = vst[i][j] + (z - vst[i][j]) * 0.5f;
        const bool sp = v >= 1.0f;
        rr[j] = sp ? 1.0f : 0.0f;
        vst[i][j] = sp ? 0.f : v;
      }
      *(float4*)(OA + (size_t)t * BCNn + (size_t)o * Nn) = *(float4*)&rr[0];
      *(float4*)(OB + (size_t)t * BCNn + (size_t)o * Nn) = *(float4*)&rr[4];
    }
  }
}

// ---------------------------------------------------------------------------
extern "C" void kernel_launch(void* const* d_in, const int* in_sizes, int n_in,
                              void* d_out, int out_size, void* d_ws, size_t ws_size,
                              hipStream_t stream) {
  const float* x      = (const float*)d_in[0];
  const float* policy = (const float*)d_in[1];
  const float* qw = (const float*)d_in[2];
  const float* qg = (const float*)d_in[3];
  const float* qb_ = (const float*)d_in[4];
  const float* qm = (const float*)d_in[5];
  const float* qv = (const float*)d_in[6];
  const float* kw = (const float*)d_in[7];
  const float* kg = (const float*)d_in[8];
  const float* kbe = (const float*)d_in[9];
  const float* km = (const float*)d_in[10];
  const float* kv = (const float*)d_in[11];
  const float* vw = (const float*)d_in[12];
  const float* vg = (const float*)d_in[13];
  const float* vbe = (const float*)d_in[14];
  const float* vm = (const float*)d_in[15];
  const float* vv = (const float*)d_in[16];
  const float* pw = (const float*)d_in[17];
  const float* pg = (const float*)d_in[18];
  const float* pbe = (const float*)d_in[19];
  const float* pm = (const float*)d_in[20];
  const float* pv = (const float*)d_in[21];
  const float* pbias = (const float*)d_in[22];

  float* Ybuf = (float*)d_ws;                 // TBCN floats (38.5 MB), reused
  u32* bq = (u32*)d_ws + TBCNn;               // 3 x PBITS u32 (3.6 MB)
  u32* bk = bq + PBITS;
  u32* bv = bk + PBITS;
  float* out = (float*)d_out;

  const dim3 gG(49, 3, 4);   // col tiles, o tiles, t
  // Q
  gemm_bn<<<gG, 256, 0, stream>>>(x, qw, qg, qb_, qm, qv, Ybuf);
  lif_pack<<<294, 256, 0, stream>>>(Ybuf, bq);
  // K
  gemm_bn<<<gG, 256, 0, stream>>>(x, kw, kg, kbe, km, kv, Ybuf);
  lif_pack<<<294, 256, 0, stream>>>(Ybuf, bk);
  // V
  gemm_bn<<<gG, 256, 0, stream>>>(x, vw, vg, vbe, vm, vv, Ybuf);
  lif_pack<<<294, 256, 0, stream>>>(Ybuf, bv);
  // Attention -> y in Ybuf, LIF(0.5) in place
  attn_kernel<<<Tn * Bn * Hn, 256, 0, stream>>>(bq, bk, bv, policy, Ybuf);
  lif_inplace<<<BCNn / 256, 256, 0, stream>>>(Ybuf, 0.5f);
  // Proj + BN + final LIF -> out
  gemm_bn_lif<<<dim3(49, 3), 256, 0, stream>>>(Ybuf, pw, pg, pbe, pm, pv, pbias, out);
}

// Round 2
// 588.806 us; speedup vs baseline: 1.3368x; 1.3368x over previous
//
#include <hip/hip_runtime.h>

typedef unsigned int u32;

#define Tn 4
#define Bn 32
#define Cn 384
#define Nn 196
#define Hn 12
#define CNn (Cn*Nn)         // 75264
#define BCNn (Bn*CNn)       // 2408448
#define BHNn (Bn*Hn*Nn)     // 75264
#define PBITS (Tn*BHNn)     // 301056
#define TBCNn (Tn*BCNn)     // 9633792

// ---------------------------------------------------------------------------
// Shared GEMM core: 128x128 block tile (cols x o), K=384, 16-k steps, 8x8
// thread tile. Register double-buffered staging (prefetch kk+1 while
// computing kk). Fragment cols (tx*4, tx*4+64) / rows (ty*4, ty*4+64):
// bank stride 4 -> 2-way aliasing only (free), vs 4-way at the old tx*8.
// ---------------------------------------------------------------------------
__device__ __forceinline__ void gemm_tile(
    const float* __restrict__ Xt,   // X + t*BCN, layout [b,c,n]
    const float* __restrict__ W,    // [o, c] row-major, 384 wide
    int col0, int o0,
    float (* __restrict__ Xs)[132], float (* __restrict__ Ws)[132],
    float acc[8][8])
{
  const int tid = threadIdx.x;
  const int tx = tid & 15, ty = tid >> 4;
  // X staging: 2 float4/thread covering 16c x 128col
  const int xi1 = tid + 256;
  const int xc0 = tid >> 5, xcol0 = (tid & 31) * 4;
  const int xc1 = xi1 >> 5, xcol1 = (xi1 & 31) * 4;
  const int cg0 = col0 + xcol0; const int bg0 = cg0 / Nn; const int ng0 = cg0 - bg0 * Nn;
  const int cg1 = col0 + xcol1; const int bg1 = cg1 / Nn; const int ng1 = cg1 - bg1 * Nn;
  const float* Xp0 = Xt + (size_t)bg0 * CNn + ng0;
  const float* Xp1 = Xt + (size_t)bg1 * CNn + ng1;
  // W staging: 2 float4/thread covering 128o x 16c (transposed into LDS)
  const int wo0 = tid >> 2;
  const int wc0 = (tid & 3) * 4;
  const float* Wp0 = W + (size_t)(o0 + wo0) * Cn + wc0;
  const float* Wp1 = W + (size_t)(o0 + wo0 + 64) * Cn + wc0;

  float4 xa = *(const float4*)(Xp0 + (size_t)xc0 * Nn);
  float4 xb = *(const float4*)(Xp1 + (size_t)xc1 * Nn);
  float4 wa = *(const float4*)(Wp0);
  float4 wb = *(const float4*)(Wp1);

  for (int kk = 0; kk < 24; ++kk) {
    __syncthreads();   // previous compute done reading LDS
    *(float4*)(&Xs[xc0][xcol0]) = xa;
    *(float4*)(&Xs[xc1][xcol1]) = xb;
    Ws[wc0 + 0][wo0] = wa.x; Ws[wc0 + 1][wo0] = wa.y;
    Ws[wc0 + 2][wo0] = wa.z; Ws[wc0 + 3][wo0] = wa.w;
    Ws[wc0 + 0][wo0 + 64] = wb.x; Ws[wc0 + 1][wo0 + 64] = wb.y;
    Ws[wc0 + 2][wo0 + 64] = wb.z; Ws[wc0 + 3][wo0 + 64] = wb.w;
    __syncthreads();
    if (kk < 23) {  // prefetch next k-slab; latency hides behind compute
      const int c = (kk + 1) * 16;
      xa = *(const float4*)(Xp0 + (size_t)(c + xc0) * Nn);
      xb = *(const float4*)(Xp1 + (size_t)(c + xc1) * Nn);
      wa = *(const float4*)(Wp0 + c);
      wb = *(const float4*)(Wp1 + c);
    }
#pragma unroll
    for (int cs = 0; cs < 16; ++cs) {
      float xr[8], wr[8];
      *(float4*)&xr[0] = *(const float4*)(&Xs[cs][tx * 4]);
      *(float4*)&xr[4] = *(const float4*)(&Xs[cs][tx * 4 + 64]);
      *(float4*)&wr[0] = *(const float4*)(&Ws[cs][ty * 4]);
      *(float4*)&wr[4] = *(const float4*)(&Ws[cs][ty * 4 + 64]);
#pragma unroll
      for (int i = 0; i < 8; i++)
#pragma unroll
        for (int j = 0; j < 8; j++)
          acc[i][j] += wr[i] * xr[j];
    }
  }
}

struct QKVArgs {
  const float* w[3]; const float* g[3]; const float* be[3];
  const float* mu[3]; const float* va[3]; float* y[3];
};

// ---------------------------------------------------------------------------
// K1 (main path): fused Q/K/V GEMM+BN, grid (49, 9, 4) = 1764 blocks.
// ---------------------------------------------------------------------------
__global__ __launch_bounds__(256) void gemm_qkv(
    const float* __restrict__ X, QKVArgs A)
{
  __shared__ float Xs[16][132];
  __shared__ float Ws[16][132];
  const int p = blockIdx.y / 3;            // which projection (q,k,v)
  const int ot = blockIdx.y - p * 3;
  const int col0 = blockIdx.x * 128;
  const int o0 = ot * 128;
  const int t = blockIdx.z;
  float acc[8][8] = {};
  gemm_tile(X + (size_t)t * BCNn, A.w[p], col0, o0, Xs, Ws, acc);

  const int tid = threadIdx.x;
  const int tx = tid & 15, ty = tid >> 4;
  const int colA = col0 + tx * 4; const int bA = colA / Nn, nA = colA - bA * Nn;
  const int colB = colA + 64;     const int bB = colB / Nn, nB = colB - bB * Nn;
  float* YA = A.y[p] + (size_t)t * BCNn + (size_t)bA * CNn + nA;
  float* YB = A.y[p] + (size_t)t * BCNn + (size_t)bB * CNn + nB;
  const float* g = A.g[p]; const float* be = A.be[p];
  const float* mu = A.mu[p]; const float* va = A.va[p];
#pragma unroll
  for (int i = 0; i < 8; i++) {
    const int o = o0 + ((i < 4) ? (ty * 4 + i) : (64 + ty * 4 + i - 4));
    const float iv = g[o] / sqrtf(va[o] + 1e-5f);
    const float sh = be[o] - mu[o] * iv;
    float4 ra, rb;
    ra.x = acc[i][0] * iv + sh; ra.y = acc[i][1] * iv + sh;
    ra.z = acc[i][2] * iv + sh; ra.w = acc[i][3] * iv + sh;
    rb.x = acc[i][4] * iv + sh; rb.y = acc[i][5] * iv + sh;
    rb.z = acc[i][6] * iv + sh; rb.w = acc[i][7] * iv + sh;
    *(float4*)(YA + (size_t)o * Nn) = ra;
    *(float4*)(YB + (size_t)o * Nn) = rb;
  }
}

// ---------------------------------------------------------------------------
// Generic single-projection GEMM + (bias) + BN, t-parallel. grid (49,3,4).
// Used for proj (main path, has_bias=1) and QKV fallback (has_bias=0).
// ---------------------------------------------------------------------------
__global__ __launch_bounds__(256) void gemm_bn_g(
    const float* __restrict__ X, const float* __restrict__ W,
    const float* __restrict__ g, const float* __restrict__ be,
    const float* __restrict__ mu, const float* __restrict__ va,
    const float* __restrict__ bias, int has_bias, float* __restrict__ Y)
{
  __shared__ float Xs[16][132];
  __shared__ float Ws[16][132];
  const int col0 = blockIdx.x * 128;
  const int o0 = blockIdx.y * 128;
  const int t = blockIdx.z;
  float acc[8][8] = {};
  gemm_tile(X + (size_t)t * BCNn, W, col0, o0, Xs, Ws, acc);

  const int tid = threadIdx.x;
  const int tx = tid & 15, ty = tid >> 4;
  const int colA = col0 + tx * 4; const int bA = colA / Nn, nA = colA - bA * Nn;
  const int colB = colA + 64;     const int bB = colB / Nn, nB = colB - bB * Nn;
  float* YA = Y + (size_t)t * BCNn + (size_t)bA * CNn + nA;
  float* YB = Y + (size_t)t * BCNn + (size_t)bB * CNn + nB;
#pragma unroll
  for (int i = 0; i < 8; i++) {
    const int o = o0 + ((i < 4) ? (ty * 4 + i) : (64 + ty * 4 + i - 4));
    const float iv = g[o] / sqrtf(va[o] + 1e-5f);
    const float sh = be[o] - mu[o] * iv;
    const float pb = has_bias ? bias[o] : 0.0f;
    float4 ra, rb;
    if (has_bias) {
      ra.x = (acc[i][0] + pb) * iv + sh; ra.y = (acc[i][1] + pb) * iv + sh;
      ra.z = (acc[i][2] + pb) * iv + sh; ra.w = (acc[i][3] + pb) * iv + sh;
      rb.x = (acc[i][4] + pb) * iv + sh; rb.y = (acc[i][5] + pb) * iv + sh;
      rb.z = (acc[i][6] + pb) * iv + sh; rb.w = (acc[i][7] + pb) * iv + sh;
    } else {
      ra.x = acc[i][0] * iv + sh; ra.y = acc[i][1] * iv + sh;
      ra.z = acc[i][2] * iv + sh; ra.w = acc[i][3] * iv + sh;
      rb.x = acc[i][4] * iv + sh; rb.y = acc[i][5] * iv + sh;
      rb.z = acc[i][6] * iv + sh; rb.w = acc[i][7] * iv + sh;
    }
    *(float4*)(YA + (size_t)o * Nn) = ra;
    *(float4*)(YB + (size_t)o * Nn) = rb;
  }
}

// ---------------------------------------------------------------------------
// Fallback proj: GEMM + bias + BN + LIF fused (t-loop inside). grid (49,3).
// ---------------------------------------------------------------------------
__global__ __launch_bounds__(256) void gemm_bn_lif(
    const float* __restrict__ X, const float* __restrict__ W,
    const float* __restrict__ g, const float* __restrict__ be,
    const float* __restrict__ mu, const float* __restrict__ va,
    const float* __restrict__ bias, float* __restrict__ Out)
{
  __shared__ float Xs[16][132];
  __shared__ float Ws[16][132];
  const int col0 = blockIdx.x * 128;
  const int o0 = blockIdx.y * 128;
  const int tid = threadIdx.x;
  const int tx = tid & 15, ty = tid >> 4;

  float iv8[8], sh8[8], pb8[8];
#pragma unroll
  for (int i = 0; i < 8; i++) {
    const int o = o0 + ((i < 4) ? (ty * 4 + i) : (64 + ty * 4 + i - 4));
    const float iv = g[o] / sqrtf(va[o] + 1e-5f);
    iv8[i] = iv; sh8[i] = be[o] - mu[o] * iv; pb8[i] = bias[o];
  }
  const int colA = col0 + tx * 4; const int bA = colA / Nn, nA = colA - bA * Nn;
  const int colB = colA + 64;     const int bB = colB / Nn, nB = colB - bB * Nn;
  float* OA = Out + (size_t)bA * CNn + nA;
  float* OB = Out + (size_t)bB * CNn + nB;

  float vst[8][8] = {};
  for (int t = 0; t < Tn; t++) {
    float acc[8][8] = {};
    gemm_tile(X + (size_t)t * BCNn, W, col0, o0, Xs, Ws, acc);
#pragma unroll
    for (int i = 0; i < 8; i++) {
      const int o = o0 + ((i < 4) ? (ty * 4 + i) : (64 + ty * 4 + i - 4));
      float rr[8];
#pragma unroll
      for (int j = 0; j < 8; j++) {
        const float z = (acc[i][j] + pb8[i]) * iv8[i] + sh8[i];
        const float v = vst[i][j] + (z - vst[i][j]) * 0.5f;
        const bool sp = v >= 1.0f;
        rr[j] = sp ? 1.0f : 0.0f;
        vst[i][j] = sp ? 0.f : v;
      }
      *(float4*)(OA + (size_t)t * BCNn + (size_t)o * Nn) = *(float4*)&rr[0];
      *(float4*)(OB + (size_t)t * BCNn + (size_t)o * Nn) = *(float4*)&rr[4];
    }
  }
}

// ---------------------------------------------------------------------------
// LIF(th=1) + pack 32 channels (one head) into u32. One thread per (b,h,n).
// ---------------------------------------------------------------------------
__device__ __forceinline__ void lif_pack_body(
    const float* __restrict__ Y, u32* __restrict__ bits, int idx)
{
  const int n = idx % Nn;
  const int hb = idx / Nn;
  const int h = hb % Hn;
  const int b = hb / Hn;
  float v[32];
#pragma unroll
  for (int d = 0; d < 32; d++) v[d] = 0.f;
#pragma unroll
  for (int t = 0; t < Tn; t++) {
    const float* p = Y + (size_t)(t * Bn + b) * CNn + (size_t)(h * 32) * Nn + n;
    u32 m = 0;
#pragma unroll
    for (int d = 0; d < 32; d++) {
      const float x = p[(size_t)d * Nn];
      const float vv = v[d] + (x - v[d]) * 0.5f;
      const bool sp = vv >= 1.0f;
      m |= (u32)(sp ? 1u : 0u) << d;
      v[d] = sp ? 0.f : vv;
    }
    bits[(size_t)t * BHNn + idx] = m;
  }
}

__global__ __launch_bounds__(256) void lif_pack(
    const float* __restrict__ Y, u32* __restrict__ bits)
{
  lif_pack_body(Y, bits, blockIdx.x * 256 + threadIdx.x);
}

__global__ __launch_bounds__(256) void lif_pack3(
    const float* __restrict__ Yq, const float* __restrict__ Yk,
    const float* __restrict__ Yv, u32* __restrict__ bq,
    u32* __restrict__ bk, u32* __restrict__ bv)
{
  const int p = blockIdx.x / 294;
  const int idx = (blockIdx.x - p * 294) * 256 + threadIdx.x;
  if (p == 0)      lif_pack_body(Yq, bq, idx);
  else if (p == 1) lif_pack_body(Yk, bk, idx);
  else             lif_pack_body(Yv, bv, idx);
}

// ---------------------------------------------------------------------------
// Attention per (t,b,h): popcount QK^T (exact), policy mask, fp32 PV.
// ---------------------------------------------------------------------------
__global__ __launch_bounds__(256) void attn_kernel(
    const u32* __restrict__ qb, const u32* __restrict__ kb,
    const u32* __restrict__ vb, const float* __restrict__ policy,
    float* __restrict__ Y)
{
  __shared__ u32 qs[Nn], ks[Nn], vs[Nn];
  __shared__ float ps[Nn];
  __shared__ float vf[Nn * 32];
  const int gid = blockIdx.x;          // (t*B+b)*H + h
  const int tb = gid / Hn;
  const int h = gid - tb * Hn;
  const int tid = threadIdx.x;
  for (int i = tid; i < Nn; i += 256) {
    qs[i] = qb[(size_t)gid * Nn + i];
    ks[i] = kb[(size_t)gid * Nn + i];
    vs[i] = vb[(size_t)gid * Nn + i];
    ps[i] = policy[(size_t)tb * Nn + i];
  }
  __syncthreads();
  for (int i = tid; i < Nn * 32; i += 256)
    vf[i] = (float)((vs[i >> 5] >> (i & 31)) & 1u);
  __syncthreads();
  const int n = tid;
  if (n < Nn) {
    const u32 qn = qs[n];
    float acc[32];
#pragma unroll
    for (int d = 0; d < 32; d++) acc[d] = 0.f;
    for (int m = 0; m < Nn; m++) {
      const u32 a = __popc(qn & ks[m]);
      if (a) {  // skipping adds exact zeros: fp32 sum unchanged
        const float pm = ps[m];
        const float mask = (m == n) ? (pm + (1.0f - pm)) : pm;
        const float w = (float)a * mask;
        const float4* vr = (const float4*)(vf + m * 32);
#pragma unroll
        for (int q = 0; q < 8; q++) {
          const float4 vv = vr[q];
          acc[q * 4 + 0] += w * vv.x; acc[q * 4 + 1] += w * vv.y;
          acc[q * 4 + 2] += w * vv.z; acc[q * 4 + 3] += w * vv.w;
        }
      }
    }
    const int t = tb / Bn, b = tb - (tb / Bn) * Bn;
    float* outp = Y + (size_t)t * BCNn + (size_t)b * CNn + (size_t)(h * 32) * Nn + n;
#pragma unroll
    for (int d = 0; d < 32; d++) outp[(size_t)d * Nn] = acc[d] * 0.25f;
  }
}

// ---------------------------------------------------------------------------
// In-place LIF over T. Per-thread same addresses -> race-free.
// ---------------------------------------------------------------------------
__global__ __launch_bounds__(256) void lif_inplace(float* __restrict__ Y, float thr)
{
  const size_t pos = (size_t)blockIdx.x * 256 + threadIdx.x;
  float v = 0.f;
#pragma unroll
  for (int t = 0; t < Tn; t++) {
    const float x = Y[(size_t)t * BCNn + pos];
    v = v + (x - v) * 0.5f;
    const bool sp = v >= thr;
    Y[(size_t)t * BCNn + pos] = sp ? 1.0f : 0.0f;
    v = sp ? 0.f : v;
  }
}

// Out-of-place final LIF (th=1.0): Z (pre-LIF) -> binary Out.
__global__ __launch_bounds__(256) void lif_out(
    const float* __restrict__ Z, float* __restrict__ Out)
{
  const size_t pos = (size_t)blockIdx.x * 256 + threadIdx.x;
  float v = 0.f;
#pragma unroll
  for (int t = 0; t < Tn; t++) {
    const float x = Z[(size_t)t * BCNn + pos];
    v = v + (x - v) * 0.5f;
    const bool sp = v >= 1.0f;
    Out[(size_t)t * BCNn + pos] = sp ? 1.0f : 0.0f;
    v = sp ? 0.f : v;
  }
}

// ---------------------------------------------------------------------------
extern "C" void kernel_launch(void* const* d_in, const int* in_sizes, int n_in,
                              void* d_out, int out_size, void* d_ws, size_t ws_size,
                              hipStream_t stream) {
  const float* x      = (const float*)d_in[0];
  const float* policy = (const float*)d_in[1];
  const float* qw = (const float*)d_in[2];
  const float* qg = (const float*)d_in[3];
  const float* qb_ = (const float*)d_in[4];
  const float* qm = (const float*)d_in[5];
  const float* qv = (const float*)d_in[6];
  const float* kw = (const float*)d_in[7];
  const float* kg = (const float*)d_in[8];
  const float* kbe = (const float*)d_in[9];
  const float* km = (const float*)d_in[10];
  const float* kv = (const float*)d_in[11];
  const float* vw = (const float*)d_in[12];
  const float* vg = (const float*)d_in[13];
  const float* vbe = (const float*)d_in[14];
  const float* vm = (const float*)d_in[15];
  const float* vv = (const float*)d_in[16];
  const float* pw = (const float*)d_in[17];
  const float* pg = (const float*)d_in[18];
  const float* pbe = (const float*)d_in[19];
  const float* pm = (const float*)d_in[20];
  const float* pv = (const float*)d_in[21];
  const float* pbias = (const float*)d_in[22];
  float* out = (float*)d_out;

  const size_t need_big = ((size_t)3 * TBCNn + (size_t)3 * PBITS) * 4;

  if (ws_size >= need_big) {
    // --- main path: fused QKV (1764 blocks) + t-parallel proj ---
    float* Yq = (float*)d_ws;
    float* Yk = Yq + TBCNn;
    float* Yv = Yk + TBCNn;
    u32* bq = (u32*)(Yv + TBCNn);
    u32* bk = bq + PBITS;
    u32* bv = bk + PBITS;

    QKVArgs A;
    A.w[0] = qw; A.g[0] = qg; A.be[0] = qb_; A.mu[0] = qm; A.va[0] = qv; A.y[0] = Yq;
    A.w[1] = kw; A.g[1] = kg; A.be[1] = kbe; A.mu[1] = km; A.va[1] = kv; A.y[1] = Yk;
    A.w[2] = vw; A.g[2] = vg; A.be[2] = vbe; A.mu[2] = vm; A.va[2] = vv; A.y[2] = Yv;

    gemm_qkv<<<dim3(49, 9, 4), 256, 0, stream>>>(x, A);
    lif_pack3<<<882, 256, 0, stream>>>(Yq, Yk, Yv, bq, bk, bv);
    // attention writes into Yq (dead after pack), LIF(0.5) in place
    attn_kernel<<<Tn * Bn * Hn, 256, 0, stream>>>(bq, bk, bv, policy, Yq);
    lif_inplace<<<BCNn / 256, 256, 0, stream>>>(Yq, 0.5f);
    // proj GEMM (t-parallel) -> Yk (dead), then final LIF -> out
    gemm_bn_g<<<dim3(49, 3, 4), 256, 0, stream>>>(Yq, pw, pg, pbe, pm, pv, pbias, 1, Yk);
    lif_out<<<BCNn / 256, 256, 0, stream>>>(Yk, out);
  } else {
    // --- fallback (fits in ~42 MB): serial per-projection, fused proj ---
    float* Ybuf = (float*)d_ws;
    u32* bq = (u32*)d_ws + TBCNn;
    u32* bk = bq + PBITS;
    u32* bv = bk + PBITS;

    const dim3 gG(49, 3, 4);
    gemm_bn_g<<<gG, 256, 0, stream>>>(x, qw, qg, qb_, qm, qv, nullptr, 0, Ybuf);
    lif_pack<<<294, 256, 0, stream>>>(Ybuf, bq);
    gemm_bn_g<<<gG, 256, 0, stream>>>(x, kw, kg, kbe, km, kv, nullptr, 0, Ybuf);
    lif_pack<<<294, 256, 0, stream>>>(Ybuf, bk);
    gemm_bn_g<<<gG, 256, 0, stream>>>(x, vw, vg, vbe, vm, vv, nullptr, 0, Ybuf);
    lif_pack<<<294, 256, 0, stream>>>(Ybuf, bv);
    attn_kernel<<<Tn * Bn * Hn, 256, 0, stream>>>(bq, bk, bv, policy, Ybuf);
    lif_inplace<<<BCNn / 256, 256, 0, stream>>>(Ybuf, 0.5f);
    gemm_bn_lif<<<dim3(49, 3), 256, 0, stream>>>(Ybuf, pw, pg, pbe, pm, pv, pbias, out);
  }
}

// Round 3
// 554.338 us; speedup vs baseline: 1.4199x; 1.0622x over previous
//
#include <hip/hip_runtime.h>

typedef unsigned int u32;
typedef __bf16 bf16x8 __attribute__((ext_vector_type(8)));
typedef __bf16 bf16x4v __attribute__((ext_vector_type(4)));
typedef float f32x4 __attribute__((ext_vector_type(4)));

#define Tn 4
#define Bn 32
#define Cn 384
#define Nn 196
#define Hn 12
#define CNn (Cn*Nn)         // 75264
#define BCNn (Bn*CNn)       // 2408448
#define BHNn (Bn*Hn*Nn)     // 75264
#define PBITS (Tn*BHNn)     // 301056
#define TBCNn (Tn*BCNn)     // 9633792
#define NCOLS 6272          // B*N
#define WSZ 147456          // 384*384

// ===========================================================================
// ============================ MFMA MAIN PATH ===============================
// ===========================================================================

// fp32 -> 3-way bf16 split (exact residuals in fp32; h+m+l = x to ~2^-25)
__device__ __forceinline__ void split3(float v, __bf16& h, __bf16& m, __bf16& l) {
  h = (__bf16)v;  float r = v - (float)h;
  m = (__bf16)r;  float r2 = r - (float)m;
  l = (__bf16)r2;
}

// W [4][384][384] fp32 -> wsp [4][3][384][384] bf16 (flat, fully coalesced)
struct W4 { const float* w[4]; };
__global__ __launch_bounds__(256) void split_w(W4 a, __bf16* __restrict__ wsp) {
  const int i = blockIdx.x * 256 + threadIdx.x;   // < 589824
  const int p = i / WSZ, r = i - p * WSZ;
  __bf16 h, m, l;
  split3(a.w[p][r], h, m, l);
  wsp[(size_t)(p * 3 + 0) * WSZ + r] = h;
  wsp[(size_t)(p * 3 + 1) * WSZ + r] = m;
  wsp[(size_t)(p * 3 + 2) * WSZ + r] = l;
}

// x [t,b,c,n] fp32 -> xs_s [t][col=(b,n)][c] bf16 x3 (transpose: thread=n,
// reads coalesced across n; per-thread contiguous 16B stores per c-chunk)
__global__ __launch_bounds__(256) void split_x(
    const float* __restrict__ x, __bf16* __restrict__ xs0,
    __bf16* __restrict__ xs1, __bf16* __restrict__ xs2) {
  const int t = blockIdx.x, b = blockIdx.y, ch = blockIdx.z;
  const int n = threadIdx.x;
  if (n >= Nn) return;
  const size_t col = (size_t)b * Nn + n;
  const float* xp = x + (size_t)t * BCNn + (size_t)b * CNn + n;
  const int c0 = ch * 192;
  for (int c = c0; c < c0 + 192; c += 8) {
    __bf16 h8[8], m8[8], l8[8];
#pragma unroll
    for (int j = 0; j < 8; ++j)
      split3(xp[(size_t)(c + j) * Nn], h8[j], m8[j], l8[j]);
    const size_t o = ((size_t)t * NCOLS + col) * Cn + c;
    *(bf16x8*)&xs0[o] = *(bf16x8*)h8;
    *(bf16x8*)&xs1[o] = *(bf16x8*)m8;
    *(bf16x8*)&xs2[o] = *(bf16x8*)l8;
  }
}

__device__ __forceinline__ void gl_lds16(const void* g, void* l) {
  __builtin_amdgcn_global_load_lds(
      (const __attribute__((address_space(1))) void*)g,
      (__attribute__((address_space(3))) void*)l, 16, 0, 0);
}

struct QKVOut {
  const float* g[3]; const float* be[3]; const float* mu[3]; const float* va[3];
  float* yT[3];
};

// QKV GEMM via 6-product split-bf16 MFMA. grid (9 = proj*3+mtile, 49 col, 4 t)
// Block 128 o x 128 col; 4 waves, each 64x64 = 4x4 of 16x16x32 frags.
__global__ __launch_bounds__(256, 2) void gemm_qkv_mfma(
    const __bf16* __restrict__ xs,   // [3][t][col][c]
    const __bf16* __restrict__ wsp,  // [4][3][o][c]
    QKVOut A) {
  __shared__ __bf16 Ab[3][128][32];
  __shared__ __bf16 Bb[3][128][32];
  const int tid = threadIdx.x;
  const int lane = tid & 63, wid = tid >> 6;
  const int wm = wid >> 1, wn = wid & 1;
  const int wt = blockIdx.x;
  const int p = wt / 3, mt = wt - p * 3;
  const int col0 = blockIdx.y * 128;
  const int t = blockIdx.z;
  const int o0 = mt * 128;

  const __bf16* Ag = wsp + (size_t)(p * 3) * WSZ;
  const int srow = wid * 32 + (lane >> 2);   // staging row (j adds 16)
  const int sk = (lane & 3) * 8;             // staging k-element offset

  f32x4 acc[4][4] = {};

  for (int kk = 0; kk < 12; ++kk) {
    const int k0 = kk * 32;
#pragma unroll
    for (int s = 0; s < 3; ++s) {
#pragma unroll
      for (int j = 0; j < 2; ++j) {
        const __bf16* ga = Ag + (size_t)s * WSZ +
            (size_t)(o0 + srow + j * 16) * Cn + k0 + sk;
        const __bf16* gb = xs + (size_t)s * TBCNn +
            ((size_t)t * NCOLS + col0 + srow + j * 16) * Cn + k0 + sk;
        gl_lds16(ga, &Ab[s][wid * 32 + j * 16][0]);
        gl_lds16(gb, &Bb[s][wid * 32 + j * 16][0]);
      }
    }
    __syncthreads();
    const int fr = lane & 15, fk = (lane >> 4) * 8;
    bf16x8 af[3][4], bfr[3][4];
#pragma unroll
    for (int s = 0; s < 3; ++s)
#pragma unroll
      for (int i = 0; i < 4; ++i) {
        af[s][i]  = *(const bf16x8*)&Ab[s][wm * 64 + i * 16 + fr][fk];
        bfr[s][i] = *(const bf16x8*)&Bb[s][wn * 64 + i * 16 + fr][fk];
      }
#pragma unroll
    for (int mi = 0; mi < 4; ++mi)
#pragma unroll
      for (int ni = 0; ni < 4; ++ni) {
        f32x4 c = acc[mi][ni];
        c = __builtin_amdgcn_mfma_f32_16x16x32_bf16(af[0][mi], bfr[0][ni], c, 0, 0, 0);
        c = __builtin_amdgcn_mfma_f32_16x16x32_bf16(af[0][mi], bfr[1][ni], c, 0, 0, 0);
        c = __builtin_amdgcn_mfma_f32_16x16x32_bf16(af[1][mi], bfr[0][ni], c, 0, 0, 0);
        c = __builtin_amdgcn_mfma_f32_16x16x32_bf16(af[1][mi], bfr[1][ni], c, 0, 0, 0);
        c = __builtin_amdgcn_mfma_f32_16x16x32_bf16(af[0][mi], bfr[2][ni], c, 0, 0, 0);
        c = __builtin_amdgcn_mfma_f32_16x16x32_bf16(af[2][mi], bfr[0][ni], c, 0, 0, 0);
        acc[mi][ni] = c;
      }
    __syncthreads();
  }
  // epilogue: BN, store to yT[t][col][o] (float4 over 4 consecutive o)
  const int quad = lane >> 4, nl = lane & 15;
#pragma unroll
  for (int mi = 0; mi < 4; ++mi) {
    const int ob = o0 + wm * 64 + mi * 16 + quad * 4;
    f32x4 gv = *(const f32x4*)&A.g[p][ob];
    f32x4 vv = *(const f32x4*)&A.va[p][ob];
    f32x4 mv = *(const f32x4*)&A.mu[p][ob];
    f32x4 bv = *(const f32x4*)&A.be[p][ob];
    f32x4 iv, sh;
#pragma unroll
    for (int r = 0; r < 4; ++r) {
      iv[r] = gv[r] / sqrtf(vv[r] + 1e-5f);
      sh[r] = bv[r] - mv[r] * iv[r];
    }
#pragma unroll
    for (int ni = 0; ni < 4; ++ni) {
      const int col = col0 + wn * 64 + ni * 16 + nl;
      f32x4 o4;
#pragma unroll
      for (int r = 0; r < 4; ++r) o4[r] = acc[mi][ni][r] * iv[r] + sh[r];
      *(f32x4*)(A.yT[p] + ((size_t)t * NCOLS + col) * Cn + ob) = o4;
    }
  }
}

// proj GEMM: A = 3-split W, B = binary spikes (exact bf16, 1 copy) -> 3 MFMAs.
// grid (3 mtile, 49 col, 4 t). Stores pre-LIF z in [t,b,o,n] layout.
__global__ __launch_bounds__(256, 2) void gemm_proj_mfma(
    const __bf16* __restrict__ sp,   // [t][col][c]
    const __bf16* __restrict__ wsp,  // [4][3][o][c], proj index 3
    const float* __restrict__ g, const float* __restrict__ be,
    const float* __restrict__ mu, const float* __restrict__ va,
    const float* __restrict__ bias, float* __restrict__ z) {
  __shared__ __bf16 Ab[3][128][32];
  __shared__ __bf16 Bb[128][32];
  const int tid = threadIdx.x;
  const int lane = tid & 63, wid = tid >> 6;
  const int wm = wid >> 1, wn = wid & 1;
  const int o0 = blockIdx.x * 128;
  const int col0 = blockIdx.y * 128;
  const int t = blockIdx.z;

  const __bf16* Ag = wsp + (size_t)9 * WSZ;   // proj = index 3
  const int srow = wid * 32 + (lane >> 2);
  const int sk = (lane & 3) * 8;

  f32x4 acc[4][4] = {};

  for (int kk = 0; kk < 12; ++kk) {
    const int k0 = kk * 32;
#pragma unroll
    for (int s = 0; s < 3; ++s)
#pragma unroll
      for (int j = 0; j < 2; ++j)
        gl_lds16(Ag + (size_t)s * WSZ + (size_t)(o0 + srow + j * 16) * Cn + k0 + sk,
                 &Ab[s][wid * 32 + j * 16][0]);
#pragma unroll
    for (int j = 0; j < 2; ++j)
      gl_lds16(sp + ((size_t)t * NCOLS + col0 + srow + j * 16) * Cn + k0 + sk,
               &Bb[wid * 32 + j * 16][0]);
    __syncthreads();
    const int fr = lane & 15, fk = (lane >> 4) * 8;
    bf16x8 af[3][4], bfr[4];
#pragma unroll
    for (int i = 0; i < 4; ++i) {
      bfr[i] = *(const bf16x8*)&Bb[wn * 64 + i * 16 + fr][fk];
#pragma unroll
      for (int s = 0; s < 3; ++s)
        af[s][i] = *(const bf16x8*)&Ab[s][wm * 64 + i * 16 + fr][fk];
    }
#pragma unroll
    for (int mi = 0; mi < 4; ++mi)
#pragma unroll
      for (int ni = 0; ni < 4; ++ni) {
        f32x4 c = acc[mi][ni];
        c = __builtin_amdgcn_mfma_f32_16x16x32_bf16(af[0][mi], bfr[ni], c, 0, 0, 0);
        c = __builtin_amdgcn_mfma_f32_16x16x32_bf16(af[1][mi], bfr[ni], c, 0, 0, 0);
        c = __builtin_amdgcn_mfma_f32_16x16x32_bf16(af[2][mi], bfr[ni], c, 0, 0, 0);
        acc[mi][ni] = c;
      }
    __syncthreads();
  }
  const int quad = lane >> 4, nl = lane & 15;
#pragma unroll
  for (int mi = 0; mi < 4; ++mi) {
    const int ob = o0 + wm * 64 + mi * 16 + quad * 4;
    f32x4 gv = *(const f32x4*)&g[ob];
    f32x4 vv = *(const f32x4*)&va[ob];
    f32x4 mv = *(const f32x4*)&mu[ob];
    f32x4 bv = *(const f32x4*)&be[ob];
    f32x4 pb = *(const f32x4*)&bias[ob];
    f32x4 iv, sh;
#pragma unroll
    for (int r = 0; r < 4; ++r) {
      iv[r] = gv[r] / sqrtf(vv[r] + 1e-5f);
      sh[r] = bv[r] - mv[r] * iv[r];
    }
#pragma unroll
    for (int ni = 0; ni < 4; ++ni) {
      const int col = col0 + wn * 64 + ni * 16 + nl;
      const int b = col / Nn, nn = col - b * Nn;
      float* zp = z + (size_t)t * BCNn + (size_t)b * CNn + nn;
#pragma unroll
      for (int r = 0; r < 4; ++r)
        zp[(size_t)(ob + r) * Nn] = (acc[mi][ni][r] + pb[r]) * iv[r] + sh[r];
    }
  }
}

// LIF(th=1) + bitpack from yT layout. thread = col*12+h -> contiguous 128B reads.
__global__ __launch_bounds__(256) void lif_pack3_T(
    const float* __restrict__ yTq, const float* __restrict__ yTk,
    const float* __restrict__ yTv, u32* __restrict__ bq,
    u32* __restrict__ bk, u32* __restrict__ bv) {
  const int p = blockIdx.x / 294;
  const int idx = (blockIdx.x - p * 294) * 256 + threadIdx.x;  // < 75264
  const float* yT = (p == 0) ? yTq : (p == 1) ? yTk : yTv;
  u32* bits = (p == 0) ? bq : (p == 1) ? bk : bv;
  const int h = idx % Hn, col = idx / Hn;
  const int b = col / Nn, n = col - b * Nn;
  float v[32];
#pragma unroll
  for (int d = 0; d < 32; ++d) v[d] = 0.f;
#pragma unroll
  for (int t = 0; t < Tn; ++t) {
    const f32x4* pp = (const f32x4*)(yT + ((size_t)t * NCOLS + col) * Cn + h * 32);
    u32 m = 0;
#pragma unroll
    for (int q = 0; q < 8; ++q) {
      f32x4 xx = pp[q];
#pragma unroll
      for (int r = 0; r < 4; ++r) {
        const int d = q * 4 + r;
        const float nv = v[d] + (xx[r] - v[d]) * 0.5f;
        const bool s = nv >= 1.0f;
        m |= (u32)(s ? 1u : 0u) << d;
        v[d] = s ? 0.f : nv;
      }
    }
    bits[(size_t)t * BHNn + ((size_t)b * Hn + h) * Nn + n] = m;
  }
}

// Attention per (t,b,h) -> yT[t][col][c] (c contiguous per thread)
__global__ __launch_bounds__(256) void attn_T(
    const u32* __restrict__ qb, const u32* __restrict__ kb,
    const u32* __restrict__ vb, const float* __restrict__ policy,
    float* __restrict__ yT) {
  __shared__ u32 qs[Nn], ks[Nn], vs[Nn];
  __shared__ float ps[Nn];
  __shared__ float vf[Nn * 32];
  const int gid = blockIdx.x;          // (t*B+b)*H + h
  const int tb = gid / Hn;
  const int h = gid - tb * Hn;
  const int tid = threadIdx.x;
  for (int i = tid; i < Nn; i += 256) {
    qs[i] = qb[(size_t)gid * Nn + i];
    ks[i] = kb[(size_t)gid * Nn + i];
    vs[i] = vb[(size_t)gid * Nn + i];
    ps[i] = policy[(size_t)tb * Nn + i];
  }
  __syncthreads();
  for (int i = tid; i < Nn * 32; i += 256)
    vf[i] = (float)((vs[i >> 5] >> (i & 31)) & 1u);
  __syncthreads();
  const int n = tid;
  if (n < Nn) {
    const u32 qn = qs[n];
    float acc[32];
#pragma unroll
    for (int d = 0; d < 32; ++d) acc[d] = 0.f;
    for (int m = 0; m < Nn; ++m) {
      const u32 a = __popc(qn & ks[m]);
      if (a) {  // skipped terms are exact zeros
        const float pm = ps[m];
        const float mask = (m == n) ? (pm + (1.0f - pm)) : pm;
        const float w = (float)a * mask;
        const float4* vr = (const float4*)(vf + m * 32);
#pragma unroll
        for (int q = 0; q < 8; ++q) {
          const float4 vv2 = vr[q];
          acc[q * 4 + 0] += w * vv2.x; acc[q * 4 + 1] += w * vv2.y;
          acc[q * 4 + 2] += w * vv2.z; acc[q * 4 + 3] += w * vv2.w;
        }
      }
    }
    float* outp = yT + ((size_t)tb * Nn + n) * Cn + h * 32;
#pragma unroll
    for (int q = 0; q < 8; ++q) {
      f32x4 o4;
#pragma unroll
      for (int r = 0; r < 4; ++r) o4[r] = acc[q * 4 + r] * 0.25f;
      *(f32x4*)(outp + q * 4) = o4;
    }
  }
}

// LIF(0.5) over t on yT layout, emit spikes as exact bf16 -> sp[t][col][c]
__global__ __launch_bounds__(256) void lif05_bf16(
    const float* __restrict__ yT, __bf16* __restrict__ sp) {
  const size_t i4 = ((size_t)blockIdx.x * 256 + threadIdx.x) * 4;  // < BCN
  f32x4 v = {0.f, 0.f, 0.f, 0.f};
#pragma unroll
  for (int t = 0; t < Tn; ++t) {
    f32x4 x = *(const f32x4*)(yT + (size_t)t * BCNn + i4);
    __bf16 s4[4];
#pragma unroll
    for (int r = 0; r < 4; ++r) {
      const float nv = v[r] + (x[r] - v[r]) * 0.5f;
      const bool s = nv >= 0.5f;
      s4[r] = (__bf16)(s ? 1.0f : 0.0f);
      v[r] = s ? 0.f : nv;
    }
    *(bf16x4v*)(sp + (size_t)t * BCNn + i4) = *(bf16x4v*)s4;
  }
}

// final LIF(1.0): z [t,b,o,n] fp32 -> out binary fp32, float4 vectorized
__global__ __launch_bounds__(256) void lif_out_v4(
    const float* __restrict__ z, float* __restrict__ out) {
  const size_t i4 = ((size_t)blockIdx.x * 256 + threadIdx.x) * 4;
  f32x4 v = {0.f, 0.f, 0.f, 0.f};
#pragma unroll
  for (int t = 0; t < Tn; ++t) {
    f32x4 x = *(const f32x4*)(z + (size_t)t * BCNn + i4);
    f32x4 o4;
#pragma unroll
    for (int r = 0; r < 4; ++r) {
      const float nv = v[r] + (x[r] - v[r]) * 0.5f;
      const bool s = nv >= 1.0f;
      o4[r] = s ? 1.0f : 0.0f;
      v[r] = s ? 0.f : nv;
    }
    *(f32x4*)(out + (size_t)t * BCNn + i4) = o4;
  }
}

// ===========================================================================
// ===================== R2 fp32 FALLBACK (ws < 181 MB) ======================
// ===========================================================================

__device__ __forceinline__ void gemm_tile(
    const float* __restrict__ Xt, const float* __restrict__ W,
    int col0, int o0, float (* __restrict__ Xs)[132],
    float (* __restrict__ Ws)[132], float acc[8][8]) {
  const int tid = threadIdx.x;
  const int tx = tid & 15, ty = tid >> 4;
  const int xi1 = tid + 256;
  const int xc0 = tid >> 5, xcol0 = (tid & 31) * 4;
  const int xc1 = xi1 >> 5, xcol1 = (xi1 & 31) * 4;
  const int cg0 = col0 + xcol0; const int bg0 = cg0 / Nn; const int ng0 = cg0 - bg0 * Nn;
  const int cg1 = col0 + xcol1; const int bg1 = cg1 / Nn; const int ng1 = cg1 - bg1 * Nn;
  const float* Xp0 = Xt + (size_t)bg0 * CNn + ng0;
  const float* Xp1 = Xt + (size_t)bg1 * CNn + ng1;
  const int wo0 = tid >> 2;
  const int wc0 = (tid & 3) * 4;
  const float* Wp0 = W + (size_t)(o0 + wo0) * Cn + wc0;
  const float* Wp1 = W + (size_t)(o0 + wo0 + 64) * Cn + wc0;
  float4 xa = *(const float4*)(Xp0 + (size_t)xc0 * Nn);
  float4 xb = *(const float4*)(Xp1 + (size_t)xc1 * Nn);
  float4 wa = *(const float4*)(Wp0);
  float4 wb = *(const float4*)(Wp1);
  for (int kk = 0; kk < 24; ++kk) {
    __syncthreads();
    *(float4*)(&Xs[xc0][xcol0]) = xa;
    *(float4*)(&Xs[xc1][xcol1]) = xb;
    Ws[wc0 + 0][wo0] = wa.x; Ws[wc0 + 1][wo0] = wa.y;
    Ws[wc0 + 2][wo0] = wa.z; Ws[wc0 + 3][wo0] = wa.w;
    Ws[wc0 + 0][wo0 + 64] = wb.x; Ws[wc0 + 1][wo0 + 64] = wb.y;
    Ws[wc0 + 2][wo0 + 64] = wb.z; Ws[wc0 + 3][wo0 + 64] = wb.w;
    __syncthreads();
    if (kk < 23) {
      const int c = (kk + 1) * 16;
      xa = *(const float4*)(Xp0 + (size_t)(c + xc0) * Nn);
      xb = *(const float4*)(Xp1 + (size_t)(c + xc1) * Nn);
      wa = *(const float4*)(Wp0 + c);
      wb = *(const float4*)(Wp1 + c);
    }
#pragma unroll
    for (int cs = 0; cs < 16; ++cs) {
      float xr[8], wr[8];
      *(float4*)&xr[0] = *(const float4*)(&Xs[cs][tx * 4]);
      *(float4*)&xr[4] = *(const float4*)(&Xs[cs][tx * 4 + 64]);
      *(float4*)&wr[0] = *(const float4*)(&Ws[cs][ty * 4]);
      *(float4*)&wr[4] = *(const float4*)(&Ws[cs][ty * 4 + 64]);
#pragma unroll
      for (int i = 0; i < 8; i++)
#pragma unroll
        for (int j = 0; j < 8; j++)
          acc[i][j] += wr[i] * xr[j];
    }
  }
}

struct QKVArgs {
  const float* w[3]; const float* g[3]; const float* be[3];
  const float* mu[3]; const float* va[3]; float* y[3];
};

__global__ __launch_bounds__(256) void gemm_qkv_f32(
    const float* __restrict__ X, QKVArgs A) {
  __shared__ float Xs[16][132];
  __shared__ float Ws[16][132];
  const int p = blockIdx.y / 3;
  const int ot = blockIdx.y - p * 3;
  const int col0 = blockIdx.x * 128;
  const int o0 = ot * 128;
  const int t = blockIdx.z;
  float acc[8][8] = {};
  gemm_tile(X + (size_t)t * BCNn, A.w[p], col0, o0, Xs, Ws, acc);
  const int tid = threadIdx.x;
  const int tx = tid & 15, ty = tid >> 4;
  const int colA = col0 + tx * 4; const int bA = colA / Nn, nA = colA - bA * Nn;
  const int colB = colA + 64;     const int bB = colB / Nn, nB = colB - bB * Nn;
  float* YA = A.y[p] + (size_t)t * BCNn + (size_t)bA * CNn + nA;
  float* YB = A.y[p] + (size_t)t * BCNn + (size_t)bB * CNn + nB;
#pragma unroll
  for (int i = 0; i < 8; i++) {
    const int o = o0 + ((i < 4) ? (ty * 4 + i) : (64 + ty * 4 + i - 4));
    const float iv = A.g[p][o] / sqrtf(A.va[p][o] + 1e-5f);
    const float sh = A.be[p][o] - A.mu[p][o] * iv;
    float4 ra, rb;
    ra.x = acc[i][0] * iv + sh; ra.y = acc[i][1] * iv + sh;
    ra.z = acc[i][2] * iv + sh; ra.w = acc[i][3] * iv + sh;
    rb.x = acc[i][4] * iv + sh; rb.y = acc[i][5] * iv + sh;
    rb.z = acc[i][6] * iv + sh; rb.w = acc[i][7] * iv + sh;
    *(float4*)(YA + (size_t)o * Nn) = ra;
    *(float4*)(YB + (size_t)o * Nn) = rb;
  }
}

__global__ __launch_bounds__(256) void gemm_bn_g(
    const float* __restrict__ X, const float* __restrict__ W,
    const float* __restrict__ g, const float* __restrict__ be,
    const float* __restrict__ mu, const float* __restrict__ va,
    const float* __restrict__ bias, int has_bias, float* __restrict__ Y) {
  __shared__ float Xs[16][132];
  __shared__ float Ws[16][132];
  const int col0 = blockIdx.x * 128;
  const int o0 = blockIdx.y * 128;
  const int t = blockIdx.z;
  float acc[8][8] = {};
  gemm_tile(X + (size_t)t * BCNn, W, col0, o0, Xs, Ws, acc);
  const int tid = threadIdx.x;
  const int tx = tid & 15, ty = tid >> 4;
  const int colA = col0 + tx * 4; const int bA = colA / Nn, nA = colA - bA * Nn;
  const int colB = colA + 64;     const int bB = colB / Nn, nB = colB - bB * Nn;
  float* YA = Y + (size_t)t * BCNn + (size_t)bA * CNn + nA;
  float* YB = Y + (size_t)t * BCNn + (size_t)bB * CNn + nB;
#pragma unroll
  for (int i = 0; i < 8; i++) {
    const int o = o0 + ((i < 4) ? (ty * 4 + i) : (64 + ty * 4 + i - 4));
    const float iv = g[o] / sqrtf(va[o] + 1e-5f);
    const float sh = be[o] - mu[o] * iv;
    const float pb = has_bias ? bias[o] : 0.0f;
    float4 ra, rb;
    ra.x = (acc[i][0] + pb) * iv + sh; ra.y = (acc[i][1] + pb) * iv + sh;
    ra.z = (acc[i][2] + pb) * iv + sh; ra.w = (acc[i][3] + pb) * iv + sh;
    rb.x = (acc[i][4] + pb) * iv + sh; rb.y = (acc[i][5] + pb) * iv + sh;
    rb.z = (acc[i][6] + pb) * iv + sh; rb.w = (acc[i][7] + pb) * iv + sh;
    *(float4*)(YA + (size_t)o * Nn) = ra;
    *(float4*)(YB + (size_t)o * Nn) = rb;
  }
}

__device__ __forceinline__ void lif_pack_body(
    const float* __restrict__ Y, u32* __restrict__ bits, int idx) {
  const int n = idx % Nn;
  const int hb = idx / Nn;
  const int h = hb % Hn;
  const int b = hb / Hn;
  float v[32];
#pragma unroll
  for (int d = 0; d < 32; d++) v[d] = 0.f;
#pragma unroll
  for (int t = 0; t < Tn; t++) {
    const float* p = Y + (size_t)(t * Bn + b) * CNn + (size_t)(h * 32) * Nn + n;
    u32 m = 0;
#pragma unroll
    for (int d = 0; d < 32; d++) {
      const float x = p[(size_t)d * Nn];
      const float vv = v[d] + (x - v[d]) * 0.5f;
      const bool sp = vv >= 1.0f;
      m |= (u32)(sp ? 1u : 0u) << d;
      v[d] = sp ? 0.f : vv;
    }
    bits[(size_t)t * BHNn + idx] = m;
  }
}

__global__ __launch_bounds__(256) void lif_pack3(
    const float* __restrict__ Yq, const float* __restrict__ Yk,
    const float* __restrict__ Yv, u32* __restrict__ bq,
    u32* __restrict__ bk, u32* __restrict__ bv) {
  const int p = blockIdx.x / 294;
  const int idx = (blockIdx.x - p * 294) * 256 + threadIdx.x;
  if (p == 0)      lif_pack_body(Yq, bq, idx);
  else if (p == 1) lif_pack_body(Yk, bk, idx);
  else             lif_pack_body(Yv, bv, idx);
}

__global__ __launch_bounds__(256) void attn_kernel(
    const u32* __restrict__ qb, const u32* __restrict__ kb,
    const u32* __restrict__ vb, const float* __restrict__ policy,
    float* __restrict__ Y) {
  __shared__ u32 qs[Nn], ks[Nn], vs[Nn];
  __shared__ float ps[Nn];
  __shared__ float vf[Nn * 32];
  const int gid = blockIdx.x;
  const int tb = gid / Hn;
  const int h = gid - tb * Hn;
  const int tid = threadIdx.x;
  for (int i = tid; i < Nn; i += 256) {
    qs[i] = qb[(size_t)gid * Nn + i];
    ks[i] = kb[(size_t)gid * Nn + i];
    vs[i] = vb[(size_t)gid * Nn + i];
    ps[i] = policy[(size_t)tb * Nn + i];
  }
  __syncthreads();
  for (int i = tid; i < Nn * 32; i += 256)
    vf[i] = (float)((vs[i >> 5] >> (i & 31)) & 1u);
  __syncthreads();
  const int n = tid;
  if (n < Nn) {
    const u32 qn = qs[n];
    float acc[32];
#pragma unroll
    for (int d = 0; d < 32; d++) acc[d] = 0.f;
    for (int m = 0; m < Nn; m++) {
      const u32 a = __popc(qn & ks[m]);
      if (a) {
        const float pm = ps[m];
        const float mask = (m == n) ? (pm + (1.0f - pm)) : pm;
        const float w = (float)a * mask;
        const float4* vr = (const float4*)(vf + m * 32);
#pragma unroll
        for (int q = 0; q < 8; q++) {
          const float4 vv = vr[q];
          acc[q * 4 + 0] += w * vv.x; acc[q * 4 + 1] += w * vv.y;
          acc[q * 4 + 2] += w * vv.z; acc[q * 4 + 3] += w * vv.w;
        }
      }
    }
    const int t = tb / Bn, b = tb - (tb / Bn) * Bn;
    float* outp = Y + (size_t)t * BCNn + (size_t)b * CNn + (size_t)(h * 32) * Nn + n;
#pragma unroll
    for (int d = 0; d < 32; d++) outp[(size_t)d * Nn] = acc[d] * 0.25f;
  }
}

__global__ __launch_bounds__(256) void lif_inplace(float* __restrict__ Y, float thr) {
  const size_t pos = (size_t)blockIdx.x * 256 + threadIdx.x;
  float v = 0.f;
#pragma unroll
  for (int t = 0; t < Tn; t++) {
    const float x = Y[(size_t)t * BCNn + pos];
    v = v + (x - v) * 0.5f;
    const bool sp = v >= thr;
    Y[(size_t)t * BCNn + pos] = sp ? 1.0f : 0.0f;
    v = sp ? 0.f : v;
  }
}

// ===========================================================================
extern "C" void kernel_launch(void* const* d_in, const int* in_sizes, int n_in,
                              void* d_out, int out_size, void* d_ws, size_t ws_size,
                              hipStream_t stream) {
  const float* x      = (const float*)d_in[0];
  const float* policy = (const float*)d_in[1];
  const float* qw = (const float*)d_in[2];
  const float* qg = (const float*)d_in[3];
  const float* qb_ = (const float*)d_in[4];
  const float* qm = (const float*)d_in[5];
  const float* qv = (const float*)d_in[6];
  const float* kw = (const float*)d_in[7];
  const float* kg = (const float*)d_in[8];
  const float* kbe = (const float*)d_in[9];
  const float* km = (const float*)d_in[10];
  const float* kv = (const float*)d_in[11];
  const float* vw = (const float*)d_in[12];
  const float* vg = (const float*)d_in[13];
  const float* vbe = (const float*)d_in[14];
  const float* vm = (const float*)d_in[15];
  const float* vv = (const float*)d_in[16];
  const float* pw = (const float*)d_in[17];
  const float* pg = (const float*)d_in[18];
  const float* pbe = (const float*)d_in[19];
  const float* pm = (const float*)d_in[20];
  const float* pv = (const float*)d_in[21];
  const float* pbias = (const float*)d_in[22];
  float* out = (float*)d_out;

  // main-path workspace layout (bytes)
  const size_t xs_bytes  = (size_t)3 * TBCNn * 2;          //  57,802,752
  const size_t wsp_bytes = (size_t)12 * WSZ * 2;           //   3,538,944
  const size_t yT_bytes  = (size_t)TBCNn * 4;              //  38,535,168
  const size_t bits_bytes = (size_t)3 * PBITS * 4;         //   3,612,672
  const size_t need_mfma = xs_bytes + wsp_bytes + 3 * yT_bytes + bits_bytes;

  if (ws_size >= need_mfma) {
    char* base = (char*)d_ws;
    __bf16* xs  = (__bf16*)base;                            // 3 split arrays
    __bf16* wsp = (__bf16*)(base + xs_bytes);
    float* yTq = (float*)(base + xs_bytes + wsp_bytes);
    float* yTk = yTq + TBCNn;
    float* yTv = yTk + TBCNn;
    u32* bq = (u32*)(base + xs_bytes + wsp_bytes + 3 * yT_bytes);
    u32* bk = bq + PBITS;
    u32* bv = bk + PBITS;
    __bf16* sp = (__bf16*)yTk;   // alias: yTk dead after pack
    float* z = yTv;              // alias: yTv dead after pack

    W4 w4; w4.w[0] = qw; w4.w[1] = kw; w4.w[2] = vw; w4.w[3] = pw;
    split_w<<<2304, 256, 0, stream>>>(w4, wsp);
    split_x<<<dim3(4, 32, 2), 256, 0, stream>>>(x, xs, xs + TBCNn, xs + 2 * TBCNn);

    QKVOut A;
    A.g[0] = qg; A.be[0] = qb_; A.mu[0] = qm; A.va[0] = qv; A.yT[0] = yTq;
    A.g[1] = kg; A.be[1] = kbe; A.mu[1] = km; A.va[1] = kv; A.yT[1] = yTk;
    A.g[2] = vg; A.be[2] = vbe; A.mu[2] = vm; A.va[2] = vv; A.yT[2] = yTv;
    gemm_qkv_mfma<<<dim3(9, 49, 4), 256, 0, stream>>>(xs, wsp, A);
    lif_pack3_T<<<882, 256, 0, stream>>>(yTq, yTk, yTv, bq, bk, bv);
    attn_T<<<Tn * Bn * Hn, 256, 0, stream>>>(bq, bk, bv, policy, yTq);
    lif05_bf16<<<BCNn / 1024, 256, 0, stream>>>(yTq, sp);
    gemm_proj_mfma<<<dim3(3, 49, 4), 256, 0, stream>>>(sp, wsp, pg, pbe, pm, pv, pbias, z);
    lif_out_v4<<<BCNn / 1024, 256, 0, stream>>>(z, out);
  } else {
    // R2 fp32 fallback (needs ~119.4 MB, known to fit)
    float* Yq = (float*)d_ws;
    float* Yk = Yq + TBCNn;
    float* Yv = Yk + TBCNn;
    u32* bq = (u32*)(Yv + TBCNn);
    u32* bk = bq + PBITS;
    u32* bv = bk + PBITS;
    QKVArgs A;
    A.w[0] = qw; A.g[0] = qg; A.be[0] = qb_; A.mu[0] = qm; A.va[0] = qv; A.y[0] = Yq;
    A.w[1] = kw; A.g[1] = kg; A.be[1] = kbe; A.mu[1] = km; A.va[1] = kv; A.y[1] = Yk;
    A.w[2] = vw; A.g[2] = vg; A.be[2] = vbe; A.mu[2] = vm; A.va[2] = vv; A.y[2] = Yv;
    gemm_qkv_f32<<<dim3(49, 9, 4), 256, 0, stream>>>(x, A);
    lif_pack3<<<882, 256, 0, stream>>>(Yq, Yk, Yv, bq, bk, bv);
    attn_kernel<<<Tn * Bn * Hn, 256, 0, stream>>>(bq, bk, bv, policy, Yq);
    lif_inplace<<<BCNn / 256, 256, 0, stream>>>(Yq, 0.5f);
    gemm_bn_g<<<dim3(49, 3, 4), 256, 0, stream>>>(Yq, pw, pg, pbe, pm, pv, pbias, 1, Yk);
    // final LIF -> out (reuse lif_out_v4)
    lif_out_v4<<<BCNn / 1024, 256, 0, stream>>>(Yk, out);
  }
}

// Round 4
// 457.737 us; speedup vs baseline: 1.7196x; 1.2110x over previous
//
#include <hip/hip_runtime.h>

typedef unsigned int u32;
typedef __bf16 bf16x8 __attribute__((ext_vector_type(8)));
typedef __bf16 bf16x4v __attribute__((ext_vector_type(4)));
typedef float f32x4 __attribute__((ext_vector_type(4)));

#define Tn 4
#define Bn 32
#define Cn 384
#define Nn 196
#define Hn 12
#define CNn (Cn*Nn)         // 75264
#define BCNn (Bn*CNn)       // 2408448
#define BHNn (Bn*Hn*Nn)     // 75264
#define PBITS (Tn*BHNn)     // 301056
#define TBCNn (Tn*BCNn)     // 9633792
#define NCOLS 6272          // B*N
#define WSZ 147456          // 384*384

// ===========================================================================
// ============================ MFMA MAIN PATH ===============================
// ===========================================================================

// fp32 -> 3-way bf16 split (exact residuals in fp32; h+m+l = x to ~2^-25)
__device__ __forceinline__ void split3(float v, __bf16& h, __bf16& m, __bf16& l) {
  h = (__bf16)v;  float r = v - (float)h;
  m = (__bf16)r;  float r2 = r - (float)m;
  l = (__bf16)r2;
}

// W [4][384][384] fp32, scaled by BN iv, -> wsp [4][3][384][384] bf16.
// Also emits shv[p][o] = BN shift (+ bias*iv folded for proj).
struct WSplitArgs {
  const float* w[4]; const float* g[4]; const float* be[4];
  const float* mu[4]; const float* va[4]; const float* bias;
};
__global__ __launch_bounds__(256) void split_w(
    WSplitArgs a, __bf16* __restrict__ wsp, float* __restrict__ shv) {
  const int i = blockIdx.x * 256 + threadIdx.x;   // < 589824
  const int p = i / WSZ, r = i - p * WSZ;
  const int o = r / Cn;
  const float iv = a.g[p][o] / sqrtf(a.va[p][o] + 1e-5f);
  __bf16 h, m, l;
  split3(a.w[p][r] * iv, h, m, l);
  wsp[(size_t)(p * 3 + 0) * WSZ + r] = h;
  wsp[(size_t)(p * 3 + 1) * WSZ + r] = m;
  wsp[(size_t)(p * 3 + 2) * WSZ + r] = l;
  if (r - o * Cn == 0) {
    float sh = a.be[p][o] - a.mu[p][o] * iv;
    if (p == 3) sh += a.bias[o] * iv;     // (bias - mu)*iv + be
    shv[p * Cn + o] = sh;
  }
}

// x [t,b,c,n] fp32 -> xT [t][col=(b,n)][c] fp32 (single array; split happens
// in-kernel in the GEMM). Reads coalesced over n; 16B stores per thread.
__global__ __launch_bounds__(256) void transpose_x(
    const float* __restrict__ x, float* __restrict__ xT) {
  const int t = blockIdx.x, b = blockIdx.y, ch = blockIdx.z;
  const int n = threadIdx.x;
  if (n >= Nn) return;
  const float* xp = x + (size_t)t * BCNn + (size_t)b * CNn + n;
  float* op = xT + ((size_t)t * NCOLS + (size_t)b * Nn + n) * Cn;
  const int c0 = ch * 192;
  for (int c = c0; c < c0 + 192; c += 4) {
    f32x4 v;
#pragma unroll
    for (int j = 0; j < 4; ++j) v[j] = xp[(size_t)(c + j) * Nn];
    *(f32x4*)(op + c) = v;
  }
}

// QKV GEMM, 6-product split-bf16 MFMA, XCD-swizzled grid (1800 blocks):
// xcd=bid&7; the 9 (p,mt) variants of one (t,col) group are adjacent slots on
// the SAME XCD -> x slab is L2-resident for 8 of 9 reads.
// LDS XOR swizzle kb'=kb^((row>>1)&3) -> max 2-way bank aliasing (free).
__global__ __launch_bounds__(256, 2) void gemm_qkv_mfma(
    const float* __restrict__ xT,    // [t][col][c] fp32
    const __bf16* __restrict__ wsp,  // [4][3][o][c] (iv-scaled)
    const float* __restrict__ shv,   // [4][o]
    float* __restrict__ yT)          // 3 contiguous [t][col][o] buffers
{
  __shared__ __bf16 Asw[3][128][32];
  __shared__ __bf16 Bsw[3][128][32];
  const int bid = blockIdx.x;
  const int xcd = bid & 7, slot = bid >> 3;      // slot 0..224
  const int gl = slot / 9, v = slot - gl * 9;    // gl 0..24, v 0..8
  const int group = xcd * 25 + gl;               // 0..199
  if (group >= 196) return;
  const int colt = group % 49, t = group / 49;
  const int col0 = colt * 128;
  const int p = v / 3, mt = v - p * 3;
  const int o0 = mt * 128;
  const int tid = threadIdx.x, lane = tid & 63, wid = tid >> 6;
  const int wm = wid >> 1, wn = wid & 1;
  const __bf16* Ag = wsp + (size_t)(p * 3) * WSZ;
  const float* Bg = xT + ((size_t)t * NCOLS + col0) * Cn;

  f32x4 acc[4][4] = {};

  for (int kk = 0; kk < 12; ++kk) {
    const int k0 = kk * 32;
    // global loads into regs (independent of LDS; overlap prev MFMA)
    bf16x8 aval[6];
#pragma unroll
    for (int i = 0; i < 6; ++i) {
      const int u = tid + i * 256;
      const int s = u >> 9, rem = u & 511;
      const int row = rem >> 2, kb = rem & 3;
      aval[i] = *(const bf16x8*)(Ag + (size_t)s * WSZ +
                                 (size_t)(o0 + row) * Cn + k0 + kb * 8);
    }
    f32x4 bval[2][2];
#pragma unroll
    for (int i = 0; i < 2; ++i) {
      const int u = tid + i * 256;
      const int row = u >> 2, kb = u & 3;
      const float* src = Bg + (size_t)row * Cn + k0 + kb * 8;
      bval[i][0] = *(const f32x4*)src;
      bval[i][1] = *(const f32x4*)(src + 4);
    }
    __syncthreads();   // prev iter's frag reads done
#pragma unroll
    for (int i = 0; i < 6; ++i) {
      const int u = tid + i * 256;
      const int s = u >> 9, rem = u & 511;
      const int row = rem >> 2, kb = rem & 3;
      const int kbp = kb ^ ((row >> 1) & 3);
      *(bf16x8*)&Asw[s][row][kbp * 8] = aval[i];
    }
#pragma unroll
    for (int i = 0; i < 2; ++i) {
      const int u = tid + i * 256;
      const int row = u >> 2, kb = u & 3;
      const int kbp = kb ^ ((row >> 1) & 3);
      __bf16 h8[8], m8[8], l8[8];
#pragma unroll
      for (int j = 0; j < 8; ++j) {
        const float xv = (j < 4) ? bval[i][0][j] : bval[i][1][j - 4];
        split3(xv, h8[j], m8[j], l8[j]);
      }
      *(bf16x8*)&Bsw[0][row][kbp * 8] = *(bf16x8*)h8;
      *(bf16x8*)&Bsw[1][row][kbp * 8] = *(bf16x8*)m8;
      *(bf16x8*)&Bsw[2][row][kbp * 8] = *(bf16x8*)l8;
    }
    __syncthreads();
    const int fr = lane & 15, qd = lane >> 4;
    bf16x8 af[3][4], bfr[3][4];
#pragma unroll
    for (int i = 0; i < 4; ++i) {
      const int ra = wm * 64 + i * 16 + fr;
      const int rb = wn * 64 + i * 16 + fr;
      const int ka = (qd ^ ((ra >> 1) & 3)) * 8;
      const int kb2 = (qd ^ ((rb >> 1) & 3)) * 8;
#pragma unroll
      for (int s = 0; s < 3; ++s) {
        af[s][i]  = *(const bf16x8*)&Asw[s][ra][ka];
        bfr[s][i] = *(const bf16x8*)&Bsw[s][rb][kb2];
      }
    }
#pragma unroll
    for (int mi = 0; mi < 4; ++mi)
#pragma unroll
      for (int ni = 0; ni < 4; ++ni) {
        f32x4 c = acc[mi][ni];
        c = __builtin_amdgcn_mfma_f32_16x16x32_bf16(af[0][mi], bfr[0][ni], c, 0, 0, 0);
        c = __builtin_amdgcn_mfma_f32_16x16x32_bf16(af[0][mi], bfr[1][ni], c, 0, 0, 0);
        c = __builtin_amdgcn_mfma_f32_16x16x32_bf16(af[1][mi], bfr[0][ni], c, 0, 0, 0);
        c = __builtin_amdgcn_mfma_f32_16x16x32_bf16(af[1][mi], bfr[1][ni], c, 0, 0, 0);
        c = __builtin_amdgcn_mfma_f32_16x16x32_bf16(af[0][mi], bfr[2][ni], c, 0, 0, 0);
        c = __builtin_amdgcn_mfma_f32_16x16x32_bf16(af[2][mi], bfr[0][ni], c, 0, 0, 0);
        acc[mi][ni] = c;
      }
  }
  // epilogue: + shift (BN folded into W), store yT[t][col][o] as f32x4
  const int quad = lane >> 4, nl = lane & 15;
  float* yTp = yT + (size_t)p * TBCNn;
#pragma unroll
  for (int mi = 0; mi < 4; ++mi) {
    const int ob = o0 + wm * 64 + mi * 16 + quad * 4;
    const f32x4 sh4 = *(const f32x4*)&shv[p * Cn + ob];
#pragma unroll
    for (int ni = 0; ni < 4; ++ni) {
      const int col = col0 + wn * 64 + ni * 16 + nl;
      f32x4 o4;
#pragma unroll
      for (int r = 0; r < 4; ++r) o4[r] = acc[mi][ni][r] + sh4[r];
      *(f32x4*)(yTp + ((size_t)t * NCOLS + col) * Cn + ob) = o4;
    }
  }
}

// proj GEMM: A = iv-scaled 3-split W, B = binary spikes (exact bf16).
// Same XCD swizzle (600 blocks, 3 variants/group). z in [t,b,o,n].
__global__ __launch_bounds__(256, 2) void gemm_proj_mfma(
    const __bf16* __restrict__ sp,   // [t][col][c]
    const __bf16* __restrict__ wsp,
    const float* __restrict__ shv,
    float* __restrict__ z)
{
  __shared__ __bf16 Asw[3][128][32];
  __shared__ __bf16 Bsw[128][32];
  const int bid = blockIdx.x;
  const int xcd = bid & 7, slot = bid >> 3;      // slot 0..74
  const int gl = slot / 3, mt = slot - gl * 3;
  const int group = xcd * 25 + gl;
  if (group >= 196) return;
  const int colt = group % 49, t = group / 49;
  const int col0 = colt * 128, o0 = mt * 128;
  const int tid = threadIdx.x, lane = tid & 63, wid = tid >> 6;
  const int wm = wid >> 1, wn = wid & 1;
  const __bf16* Ag = wsp + (size_t)9 * WSZ;      // proj = index 3
  const __bf16* Bg = sp + ((size_t)t * NCOLS + col0) * Cn;

  f32x4 acc[4][4] = {};

  for (int kk = 0; kk < 12; ++kk) {
    const int k0 = kk * 32;
    bf16x8 aval[6];
#pragma unroll
    for (int i = 0; i < 6; ++i) {
      const int u = tid + i * 256;
      const int s = u >> 9, rem = u & 511;
      const int row = rem >> 2, kb = rem & 3;
      aval[i] = *(const bf16x8*)(Ag + (size_t)s * WSZ +
                                 (size_t)(o0 + row) * Cn + k0 + kb * 8);
    }
    bf16x8 bval[2];
#pragma unroll
    for (int i = 0; i < 2; ++i) {
      const int u = tid + i * 256;
      const int row = u >> 2, kb = u & 3;
      bval[i] = *(const bf16x8*)(Bg + (size_t)row * Cn + k0 + kb * 8);
    }
    __syncthreads();
#pragma unroll
    for (int i = 0; i < 6; ++i) {
      const int u = tid + i * 256;
      const int s = u >> 9, rem = u & 511;
      const int row = rem >> 2, kb = rem & 3;
      const int kbp = kb ^ ((row >> 1) & 3);
      *(bf16x8*)&Asw[s][row][kbp * 8] = aval[i];
    }
#pragma unroll
    for (int i = 0; i < 2; ++i) {
      const int u = tid + i * 256;
      const int row = u >> 2, kb = u & 3;
      const int kbp = kb ^ ((row >> 1) & 3);
      *(bf16x8*)&Bsw[row][kbp * 8] = bval[i];
    }
    __syncthreads();
    const int fr = lane & 15, qd = lane >> 4;
    bf16x8 af[3][4], bfr[4];
#pragma unroll
    for (int i = 0; i < 4; ++i) {
      const int ra = wm * 64 + i * 16 + fr;
      const int rb = wn * 64 + i * 16 + fr;
      const int ka = (qd ^ ((ra >> 1) & 3)) * 8;
      const int kb2 = (qd ^ ((rb >> 1) & 3)) * 8;
      bfr[i] = *(const bf16x8*)&Bsw[rb][kb2];
#pragma unroll
      for (int s = 0; s < 3; ++s)
        af[s][i] = *(const bf16x8*)&Asw[s][ra][ka];
    }
#pragma unroll
    for (int mi = 0; mi < 4; ++mi)
#pragma unroll
      for (int ni = 0; ni < 4; ++ni) {
        f32x4 c = acc[mi][ni];
        c = __builtin_amdgcn_mfma_f32_16x16x32_bf16(af[0][mi], bfr[ni], c, 0, 0, 0);
        c = __builtin_amdgcn_mfma_f32_16x16x32_bf16(af[1][mi], bfr[ni], c, 0, 0, 0);
        c = __builtin_amdgcn_mfma_f32_16x16x32_bf16(af[2][mi], bfr[ni], c, 0, 0, 0);
        acc[mi][ni] = c;
      }
  }
  const int quad = lane >> 4, nl = lane & 15;
#pragma unroll
  for (int mi = 0; mi < 4; ++mi) {
    const int ob = o0 + wm * 64 + mi * 16 + quad * 4;
    const f32x4 sh4 = *(const f32x4*)&shv[3 * Cn + ob];
#pragma unroll
    for (int ni = 0; ni < 4; ++ni) {
      const int col = col0 + wn * 64 + ni * 16 + nl;
      const int b = col / Nn, nn = col - b * Nn;
      float* zp = z + (size_t)t * BCNn + (size_t)b * CNn + nn;
#pragma unroll
      for (int r = 0; r < 4; ++r)
        zp[(size_t)(ob + r) * Nn] = acc[mi][ni][r] + sh4[r];
    }
  }
}

// LIF(th=1) + bitpack from yT layout (contiguous 128B reads per thread).
__global__ __launch_bounds__(256) void lif_pack3_T(
    const float* __restrict__ yTq, const float* __restrict__ yTk,
    const float* __restrict__ yTv, u32* __restrict__ bq,
    u32* __restrict__ bk, u32* __restrict__ bv) {
  const int p = blockIdx.x / 294;
  const int idx = (blockIdx.x - p * 294) * 256 + threadIdx.x;  // < 75264
  const float* yT = (p == 0) ? yTq : (p == 1) ? yTk : yTv;
  u32* bits = (p == 0) ? bq : (p == 1) ? bk : bv;
  const int h = idx % Hn, col = idx / Hn;
  const int b = col / Nn, n = col - b * Nn;
  float v[32];
#pragma unroll
  for (int d = 0; d < 32; ++d) v[d] = 0.f;
#pragma unroll
  for (int t = 0; t < Tn; ++t) {
    const f32x4* pp = (const f32x4*)(yT + ((size_t)t * NCOLS + col) * Cn + h * 32);
    u32 m = 0;
#pragma unroll
    for (int q = 0; q < 8; ++q) {
      f32x4 xx = pp[q];
#pragma unroll
      for (int r = 0; r < 4; ++r) {
        const int d = q * 4 + r;
        const float nv = v[d] + (xx[r] - v[d]) * 0.5f;
        const bool s = nv >= 1.0f;
        m |= (u32)(s ? 1u : 0u) << d;
        v[d] = s ? 0.f : nv;
      }
    }
    bits[(size_t)t * BHNn + ((size_t)b * Hn + h) * Nn + n] = m;
  }
}

// Attention per (t,b,h): popcount QK^T (exact), policy mask, fp32 PV -> yT
__global__ __launch_bounds__(256) void attn_T(
    const u32* __restrict__ qb, const u32* __restrict__ kb,
    const u32* __restrict__ vb, const float* __restrict__ policy,
    float* __restrict__ yT) {
  __shared__ u32 qs[Nn], ks[Nn], vs[Nn];
  __shared__ float ps[Nn];
  __shared__ float vf[Nn * 32];
  const int gid = blockIdx.x;          // (t*B+b)*H + h
  const int tb = gid / Hn;
  const int h = gid - tb * Hn;
  const int tid = threadIdx.x;
  for (int i = tid; i < Nn; i += 256) {
    qs[i] = qb[(size_t)gid * Nn + i];
    ks[i] = kb[(size_t)gid * Nn + i];
    vs[i] = vb[(size_t)gid * Nn + i];
    ps[i] = policy[(size_t)tb * Nn + i];
  }
  __syncthreads();
  for (int i = tid; i < Nn * 32; i += 256)
    vf[i] = (float)((vs[i >> 5] >> (i & 31)) & 1u);
  __syncthreads();
  const int n = tid;
  if (n < Nn) {
    const u32 qn = qs[n];
    float acc[32];
#pragma unroll
    for (int d = 0; d < 32; ++d) acc[d] = 0.f;
    for (int m = 0; m < Nn; ++m) {
      const u32 a = __popc(qn & ks[m]);
      if (a) {  // skipped terms are exact zeros
        const float pm = ps[m];
        const float mask = (m == n) ? (pm + (1.0f - pm)) : pm;
        const float w = (float)a * mask;
        const float4* vr = (const float4*)(vf + m * 32);
#pragma unroll
        for (int q = 0; q < 8; ++q) {
          const float4 vv2 = vr[q];
          acc[q * 4 + 0] += w * vv2.x; acc[q * 4 + 1] += w * vv2.y;
          acc[q * 4 + 2] += w * vv2.z; acc[q * 4 + 3] += w * vv2.w;
        }
      }
    }
    float* outp = yT + ((size_t)tb * Nn + n) * Cn + h * 32;
#pragma unroll
    for (int q = 0; q < 8; ++q) {
      f32x4 o4;
#pragma unroll
      for (int r = 0; r < 4; ++r) o4[r] = acc[q * 4 + r] * 0.25f;
      *(f32x4*)(outp + q * 4) = o4;
    }
  }
}

// LIF(0.5) over t on yT layout, emit spikes as exact bf16 -> sp[t][col][c]
__global__ __launch_bounds__(256) void lif05_bf16(
    const float* __restrict__ yT, __bf16* __restrict__ sp) {
  const size_t i4 = ((size_t)blockIdx.x * 256 + threadIdx.x) * 4;  // < BCN
  f32x4 v = {0.f, 0.f, 0.f, 0.f};
#pragma unroll
  for (int t = 0; t < Tn; ++t) {
    f32x4 x = *(const f32x4*)(yT + (size_t)t * BCNn + i4);
    __bf16 s4[4];
#pragma unroll
    for (int r = 0; r < 4; ++r) {
      const float nv = v[r] + (x[r] - v[r]) * 0.5f;
      const bool s = nv >= 0.5f;
      s4[r] = (__bf16)(s ? 1.0f : 0.0f);
      v[r] = s ? 0.f : nv;
    }
    *(bf16x4v*)(sp + (size_t)t * BCNn + i4) = *(bf16x4v*)s4;
  }
}

// final LIF(1.0): z [t,b,o,n] fp32 -> out binary fp32, float4 vectorized
__global__ __launch_bounds__(256) void lif_out_v4(
    const float* __restrict__ z, float* __restrict__ out) {
  const size_t i4 = ((size_t)blockIdx.x * 256 + threadIdx.x) * 4;
  f32x4 v = {0.f, 0.f, 0.f, 0.f};
#pragma unroll
  for (int t = 0; t < Tn; ++t) {
    f32x4 x = *(const f32x4*)(z + (size_t)t * BCNn + i4);
    f32x4 o4;
#pragma unroll
    for (int r = 0; r < 4; ++r) {
      const float nv = v[r] + (x[r] - v[r]) * 0.5f;
      const bool s = nv >= 1.0f;
      o4[r] = s ? 1.0f : 0.0f;
      v[r] = s ? 0.f : nv;
    }
    *(f32x4*)(out + (size_t)t * BCNn + i4) = o4;
  }
}

// ===========================================================================
// ===================== R2 fp32 FALLBACK (small ws) =========================
// ===========================================================================

__device__ __forceinline__ void gemm_tile(
    const float* __restrict__ Xt, const float* __restrict__ W,
    int col0, int o0, float (* __restrict__ Xs)[132],
    float (* __restrict__ Ws)[132], float acc[8][8]) {
  const int tid = threadIdx.x;
  const int tx = tid & 15, ty = tid >> 4;
  const int xi1 = tid + 256;
  const int xc0 = tid >> 5, xcol0 = (tid & 31) * 4;
  const int xc1 = xi1 >> 5, xcol1 = (xi1 & 31) * 4;
  const int cg0 = col0 + xcol0; const int bg0 = cg0 / Nn; const int ng0 = cg0 - bg0 * Nn;
  const int cg1 = col0 + xcol1; const int bg1 = cg1 / Nn; const int ng1 = cg1 - bg1 * Nn;
  const float* Xp0 = Xt + (size_t)bg0 * CNn + ng0;
  const float* Xp1 = Xt + (size_t)bg1 * CNn + ng1;
  const int wo0 = tid >> 2;
  const int wc0 = (tid & 3) * 4;
  const float* Wp0 = W + (size_t)(o0 + wo0) * Cn + wc0;
  const float* Wp1 = W + (size_t)(o0 + wo0 + 64) * Cn + wc0;
  float4 xa = *(const float4*)(Xp0 + (size_t)xc0 * Nn);
  float4 xb = *(const float4*)(Xp1 + (size_t)xc1 * Nn);
  float4 wa = *(const float4*)(Wp0);
  float4 wb = *(const float4*)(Wp1);
  for (int kk = 0; kk < 24; ++kk) {
    __syncthreads();
    *(float4*)(&Xs[xc0][xcol0]) = xa;
    *(float4*)(&Xs[xc1][xcol1]) = xb;
    Ws[wc0 + 0][wo0] = wa.x; Ws[wc0 + 1][wo0] = wa.y;
    Ws[wc0 + 2][wo0] = wa.z; Ws[wc0 + 3][wo0] = wa.w;
    Ws[wc0 + 0][wo0 + 64] = wb.x; Ws[wc0 + 1][wo0 + 64] = wb.y;
    Ws[wc0 + 2][wo0 + 64] = wb.z; Ws[wc0 + 3][wo0 + 64] = wb.w;
    __syncthreads();
    if (kk < 23) {
      const int c = (kk + 1) * 16;
      xa = *(const float4*)(Xp0 + (size_t)(c + xc0) * Nn);
      xb = *(const float4*)(Xp1 + (size_t)(c + xc1) * Nn);
      wa = *(const float4*)(Wp0 + c);
      wb = *(const float4*)(Wp1 + c);
    }
#pragma unroll
    for (int cs = 0; cs < 16; ++cs) {
      float xr[8], wr[8];
      *(float4*)&xr[0] = *(const float4*)(&Xs[cs][tx * 4]);
      *(float4*)&xr[4] = *(const float4*)(&Xs[cs][tx * 4 + 64]);
      *(float4*)&wr[0] = *(const float4*)(&Ws[cs][ty * 4]);
      *(float4*)&wr[4] = *(const float4*)(&Ws[cs][ty * 4 + 64]);
#pragma unroll
      for (int i = 0; i < 8; i++)
#pragma unroll
        for (int j = 0; j < 8; j++)
          acc[i][j] += wr[i] * xr[j];
    }
  }
}

struct QKVArgs {
  const float* w[3]; const float* g[3]; const float* be[3];
  const float* mu[3]; const float* va[3]; float* y[3];
};

__global__ __launch_bounds__(256) void gemm_qkv_f32(
    const float* __restrict__ X, QKVArgs A) {
  __shared__ float Xs[16][132];
  __shared__ float Ws[16][132];
  const int p = blockIdx.y / 3;
  const int ot = blockIdx.y - p * 3;
  const int col0 = blockIdx.x * 128;
  const int o0 = ot * 128;
  const int t = blockIdx.z;
  float acc[8][8] = {};
  gemm_tile(X + (size_t)t * BCNn, A.w[p], col0, o0, Xs, Ws, acc);
  const int tid = threadIdx.x;
  const int tx = tid & 15, ty = tid >> 4;
  const int colA = col0 + tx * 4; const int bA = colA / Nn, nA = colA - bA * Nn;
  const int colB = colA + 64;     const int bB = colB / Nn, nB = colB - bB * Nn;
  float* YA = A.y[p] + (size_t)t * BCNn + (size_t)bA * CNn + nA;
  float* YB = A.y[p] + (size_t)t * BCNn + (size_t)bB * CNn + nB;
#pragma unroll
  for (int i = 0; i < 8; i++) {
    const int o = o0 + ((i < 4) ? (ty * 4 + i) : (64 + ty * 4 + i - 4));
    const float iv = A.g[p][o] / sqrtf(A.va[p][o] + 1e-5f);
    const float sh = A.be[p][o] - A.mu[p][o] * iv;
    float4 ra, rb;
    ra.x = acc[i][0] * iv + sh; ra.y = acc[i][1] * iv + sh;
    ra.z = acc[i][2] * iv + sh; ra.w = acc[i][3] * iv + sh;
    rb.x = acc[i][4] * iv + sh; rb.y = acc[i][5] * iv + sh;
    rb.z = acc[i][6] * iv + sh; rb.w = acc[i][7] * iv + sh;
    *(float4*)(YA + (size_t)o * Nn) = ra;
    *(float4*)(YB + (size_t)o * Nn) = rb;
  }
}

__global__ __launch_bounds__(256) void gemm_bn_g(
    const float* __restrict__ X, const float* __restrict__ W,
    const float* __restrict__ g, const float* __restrict__ be,
    const float* __restrict__ mu, const float* __restrict__ va,
    const float* __restrict__ bias, int has_bias, float* __restrict__ Y) {
  __shared__ float Xs[16][132];
  __shared__ float Ws[16][132];
  const int col0 = blockIdx.x * 128;
  const int o0 = blockIdx.y * 128;
  const int t = blockIdx.z;
  float acc[8][8] = {};
  gemm_tile(X + (size_t)t * BCNn, W, col0, o0, Xs, Ws, acc);
  const int tid = threadIdx.x;
  const int tx = tid & 15, ty = tid >> 4;
  const int colA = col0 + tx * 4; const int bA = colA / Nn, nA = colA - bA * Nn;
  const int colB = colA + 64;     const int bB = colB / Nn, nB = colB - bB * Nn;
  float* YA = Y + (size_t)t * BCNn + (size_t)bA * CNn + nA;
  float* YB = Y + (size_t)t * BCNn + (size_t)bB * CNn + nB;
#pragma unroll
  for (int i = 0; i < 8; i++) {
    const int o = o0 + ((i < 4) ? (ty * 4 + i) : (64 + ty * 4 + i - 4));
    const float iv = g[o] / sqrtf(va[o] + 1e-5f);
    const float sh = be[o] - mu[o] * iv;
    const float pb = has_bias ? bias[o] : 0.0f;
    float4 ra, rb;
    ra.x = (acc[i][0] + pb) * iv + sh; ra.y = (acc[i][1] + pb) * iv + sh;
    ra.z = (acc[i][2] + pb) * iv + sh; ra.w = (acc[i][3] + pb) * iv + sh;
    rb.x = (acc[i][4] + pb) * iv + sh; rb.y = (acc[i][5] + pb) * iv + sh;
    rb.z = (acc[i][6] + pb) * iv + sh; rb.w = (acc[i][7] + pb) * iv + sh;
    *(float4*)(YA + (size_t)o * Nn) = ra;
    *(float4*)(YB + (size_t)o * Nn) = rb;
  }
}

__device__ __forceinline__ void lif_pack_body(
    const float* __restrict__ Y, u32* __restrict__ bits, int idx) {
  const int n = idx % Nn;
  const int hb = idx / Nn;
  const int h = hb % Hn;
  const int b = hb / Hn;
  float v[32];
#pragma unroll
  for (int d = 0; d < 32; d++) v[d] = 0.f;
#pragma unroll
  for (int t = 0; t < Tn; t++) {
    const float* p = Y + (size_t)(t * Bn + b) * CNn + (size_t)(h * 32) * Nn + n;
    u32 m = 0;
#pragma unroll
    for (int d = 0; d < 32; d++) {
      const float x = p[(size_t)d * Nn];
      const float vv = v[d] + (x - v[d]) * 0.5f;
      const bool sp = vv >= 1.0f;
      m |= (u32)(sp ? 1u : 0u) << d;
      v[d] = sp ? 0.f : vv;
    }
    bits[(size_t)t * BHNn + idx] = m;
  }
}

__global__ __launch_bounds__(256) void lif_pack3(
    const float* __restrict__ Yq, const float* __restrict__ Yk,
    const float* __restrict__ Yv, u32* __restrict__ bq,
    u32* __restrict__ bk, u32* __restrict__ bv) {
  const int p = blockIdx.x / 294;
  const int idx = (blockIdx.x - p * 294) * 256 + threadIdx.x;
  if (p == 0)      lif_pack_body(Yq, bq, idx);
  else if (p == 1) lif_pack_body(Yk, bk, idx);
  else             lif_pack_body(Yv, bv, idx);
}

__global__ __launch_bounds__(256) void attn_kernel(
    const u32* __restrict__ qb, const u32* __restrict__ kb,
    const u32* __restrict__ vb, const float* __restrict__ policy,
    float* __restrict__ Y) {
  __shared__ u32 qs[Nn], ks[Nn], vs[Nn];
  __shared__ float ps[Nn];
  __shared__ float vf[Nn * 32];
  const int gid = blockIdx.x;
  const int tb = gid / Hn;
  const int h = gid - tb * Hn;
  const int tid = threadIdx.x;
  for (int i = tid; i < Nn; i += 256) {
    qs[i] = qb[(size_t)gid * Nn + i];
    ks[i] = kb[(size_t)gid * Nn + i];
    vs[i] = vb[(size_t)gid * Nn + i];
    ps[i] = policy[(size_t)tb * Nn + i];
  }
  __syncthreads();
  for (int i = tid; i < Nn * 32; i += 256)
    vf[i] = (float)((vs[i >> 5] >> (i & 31)) & 1u);
  __syncthreads();
  const int n = tid;
  if (n < Nn) {
    const u32 qn = qs[n];
    float acc[32];
#pragma unroll
    for (int d = 0; d < 32; d++) acc[d] = 0.f;
    for (int m = 0; m < Nn; m++) {
      const u32 a = __popc(qn & ks[m]);
      if (a) {
        const float pm = ps[m];
        const float mask = (m == n) ? (pm + (1.0f - pm)) : pm;
        const float w = (float)a * mask;
        const float4* vr = (const float4*)(vf + m * 32);
#pragma unroll
        for (int q = 0; q < 8; q++) {
          const float4 vv = vr[q];
          acc[q * 4 + 0] += w * vv.x; acc[q * 4 + 1] += w * vv.y;
          acc[q * 4 + 2] += w * vv.z; acc[q * 4 + 3] += w * vv.w;
        }
      }
    }
    const int t = tb / Bn, b = tb - (tb / Bn) * Bn;
    float* outp = Y + (size_t)t * BCNn + (size_t)b * CNn + (size_t)(h * 32) * Nn + n;
#pragma unroll
    for (int d = 0; d < 32; d++) outp[(size_t)d * Nn] = acc[d] * 0.25f;
  }
}

__global__ __launch_bounds__(256) void lif_inplace(float* __restrict__ Y, float thr) {
  const size_t pos = (size_t)blockIdx.x * 256 + threadIdx.x;
  float v = 0.f;
#pragma unroll
  for (int t = 0; t < Tn; t++) {
    const float x = Y[(size_t)t * BCNn + pos];
    v = v + (x - v) * 0.5f;
    const bool sp = v >= thr;
    Y[(size_t)t * BCNn + pos] = sp ? 1.0f : 0.0f;
    v = sp ? 0.f : v;
  }
}

// ===========================================================================
extern "C" void kernel_launch(void* const* d_in, const int* in_sizes, int n_in,
                              void* d_out, int out_size, void* d_ws, size_t ws_size,
                              hipStream_t stream) {
  const float* x      = (const float*)d_in[0];
  const float* policy = (const float*)d_in[1];
  const float* qw = (const float*)d_in[2];
  const float* qg = (const float*)d_in[3];
  const float* qb_ = (const float*)d_in[4];
  const float* qm = (const float*)d_in[5];
  const float* qv = (const float*)d_in[6];
  const float* kw = (const float*)d_in[7];
  const float* kg = (const float*)d_in[8];
  const float* kbe = (const float*)d_in[9];
  const float* km = (const float*)d_in[10];
  const float* kv = (const float*)d_in[11];
  const float* vw = (const float*)d_in[12];
  const float* vg = (const float*)d_in[13];
  const float* vbe = (const float*)d_in[14];
  const float* vm = (const float*)d_in[15];
  const float* vv = (const float*)d_in[16];
  const float* pw = (const float*)d_in[17];
  const float* pg = (const float*)d_in[18];
  const float* pbe = (const float*)d_in[19];
  const float* pm = (const float*)d_in[20];
  const float* pv = (const float*)d_in[21];
  const float* pbias = (const float*)d_in[22];
  float* out = (float*)d_out;

  // main-path workspace layout (bytes)
  const size_t xT_bytes   = (size_t)TBCNn * 4;     // 38,535,168
  const size_t wsp_bytes  = (size_t)12 * WSZ * 2;  //  3,538,944
  const size_t shv_bytes  = (size_t)4 * Cn * 4;    //      6,144
  const size_t yT_bytes   = (size_t)TBCNn * 4;     // 38,535,168 x3
  const size_t bits_bytes = (size_t)3 * PBITS * 4; //  3,612,672
  const size_t need_mfma = xT_bytes + wsp_bytes + shv_bytes + 3 * yT_bytes + bits_bytes;

  if (ws_size >= need_mfma) {
    char* base = (char*)d_ws;
    float* xT   = (float*)base;
    __bf16* wsp = (__bf16*)(base + xT_bytes);
    float* shv  = (float*)(base + xT_bytes + wsp_bytes);
    float* yTq  = (float*)(base + xT_bytes + wsp_bytes + shv_bytes);
    float* yTk  = yTq + TBCNn;
    float* yTv  = yTk + TBCNn;
    u32* bq = (u32*)(base + xT_bytes + wsp_bytes + shv_bytes + 3 * yT_bytes);
    u32* bk = bq + PBITS;
    u32* bv = bk + PBITS;
    __bf16* sp = (__bf16*)yTk;   // alias: yTk dead after pack
    float* z = yTv;              // alias: yTv dead after pack

    WSplitArgs wa;
    wa.w[0] = qw; wa.g[0] = qg; wa.be[0] = qb_; wa.mu[0] = qm; wa.va[0] = qv;
    wa.w[1] = kw; wa.g[1] = kg; wa.be[1] = kbe; wa.mu[1] = km; wa.va[1] = kv;
    wa.w[2] = vw; wa.g[2] = vg; wa.be[2] = vbe; wa.mu[2] = vm; wa.va[2] = vv;
    wa.w[3] = pw; wa.g[3] = pg; wa.be[3] = pbe; wa.mu[3] = pm; wa.va[3] = pv;
    wa.bias = pbias;
    split_w<<<2304, 256, 0, stream>>>(wa, wsp, shv);
    transpose_x<<<dim3(4, 32, 2), 256, 0, stream>>>(x, xT);

    gemm_qkv_mfma<<<1800, 256, 0, stream>>>(xT, wsp, shv, yTq);
    lif_pack3_T<<<882, 256, 0, stream>>>(yTq, yTk, yTv, bq, bk, bv);
    attn_T<<<Tn * Bn * Hn, 256, 0, stream>>>(bq, bk, bv, policy, yTq);
    lif05_bf16<<<BCNn / 1024, 256, 0, stream>>>(yTq, sp);
    gemm_proj_mfma<<<600, 256, 0, stream>>>(sp, wsp, shv, z);
    lif_out_v4<<<BCNn / 1024, 256, 0, stream>>>(z, out);
  } else {
    // fp32 fallback (needs ~119.4 MB)
    float* Yq = (float*)d_ws;
    float* Yk = Yq + TBCNn;
    float* Yv = Yk + TBCNn;
    u32* bq = (u32*)(Yv + TBCNn);
    u32* bk = bq + PBITS;
    u32* bv = bk + PBITS;
    QKVArgs A;
    A.w[0] = qw; A.g[0] = qg; A.be[0] = qb_; A.mu[0] = qm; A.va[0] = qv; A.y[0] = Yq;
    A.w[1] = kw; A.g[1] = kg; A.be[1] = kbe; A.mu[1] = km; A.va[1] = kv; A.y[1] = Yk;
    A.w[2] = vw; A.g[2] = vg; A.be[2] = vbe; A.mu[2] = vm; A.va[2] = vv; A.y[2] = Yv;
    gemm_qkv_f32<<<dim3(49, 9, 4), 256, 0, stream>>>(x, A);
    lif_pack3<<<882, 256, 0, stream>>>(Yq, Yk, Yv, bq, bk, bv);
    attn_kernel<<<Tn * Bn * Hn, 256, 0, stream>>>(bq, bk, bv, policy, Yq);
    lif_inplace<<<BCNn / 256, 256, 0, stream>>>(Yq, 0.5f);
    gemm_bn_g<<<dim3(49, 3, 4), 256, 0, stream>>>(Yq, pw, pg, pbe, pm, pv, pbias, 1, Yk);
    lif_out_v4<<<BCNn / 1024, 256, 0, stream>>>(Yk, out);
  }
}